// Round 1
// baseline (5461.459 us; speedup 1.0000x reference)
//
#include <hip/hip_runtime.h>
#include <math.h>

typedef unsigned int u32;
typedef unsigned long long u64;

#define NLEV 5
#define ATOT 261888
#define NB 2
#define PRE_NMS_K 1000
#define POST_NMS_K 300

// level tables: hw, stride-shift, size, anchor offset (x3 per pixel)
__constant__ int c_dummy; // keep compiler happy

__device__ __forceinline__ u32 sortable(float f) {
  u32 s = __float_as_uint(f);
  return (s & 0x80000000u) ? ~s : (s | 0x80000000u);
}

// ---------------------------------------------------------------- weights
// Wt[k*256 + co], k = r*256 + ci, r = ky*3+kx   (from OIHW conv_w)
__global__ __launch_bounds__(256) void wt_kernel(const float* __restrict__ w,
                                                 float* __restrict__ Wt) {
  int t = blockIdx.x * 256 + threadIdx.x;   // t = k*256 + co
  int co = t & 255;
  int k = t >> 8;
  int r = k >> 8;          // 0..8
  int ci = k & 255;
  int ky = r / 3, kx = r - ky * 3;
  Wt[t] = w[(((co << 8) + ci) * 3 + ky) * 3 + kx];
}

// ---------------------------------------------------------------- conv fused
// One block: 32 pixels x 256 out-channels, K = 2304.  Epilogue computes the
// 1x1 cls (3ch) + box (12ch) convs from the relu tile in LDS and writes obj /
// delta directly in anchor order.
__global__ __launch_bounds__(256) void conv_fused(
    const float* __restrict__ in, const float* __restrict__ Wt,
    const float* __restrict__ cb, const float* __restrict__ clsw,
    const float* __restrict__ clsb, const float* __restrict__ boxw,
    const float* __restrict__ boxb, float* __restrict__ obj,
    float* __restrict__ delta, int W, int lvloff) {
  int b = blockIdx.y;
  int m0 = blockIdx.x * 32;
  int tid = threadIdx.x;
  int HW = W * W;
  const float* inb = in + (size_t)b * 256 * HW;

  __shared__ float sA[16 * 32];     // [kk][pixel]
  __shared__ float sB[16 * 256];    // [kk][co]  (reused for 1x1 weights, stride 257)
  __shared__ float sX[32 * 257];    // relu tile [pixel][co], padded

  int tm = tid >> 5;   // 0..7
  int tn = tid & 31;   // 0..31

  float acc[4][8];
#pragma unroll
  for (int i = 0; i < 4; i++)
#pragma unroll
    for (int j = 0; j < 8; j++) acc[i][j] = 0.f;

  // A-load role: pixel = tn, kk rows tm and tm+8
  int m_lp = m0 + tn;
  int py = m_lp / W;
  int px = m_lp - py * W;

  for (int kt = 0; kt < 144; ++kt) {
    int k0 = kt << 4;
    int r = k0 >> 8;
    int ci0 = k0 & 255;
    int r3 = r / 3;
    int dy = r3 - 1;
    int dx = (r - r3 * 3) - 1;
    int yy = py + dy, xx = px + dx;
    bool ok = (yy >= 0) && (yy < W) && (xx >= 0) && (xx < W);
    const float* src = inb + (size_t)(ci0 + tm) * HW + yy * W + xx;
    float a0 = 0.f, a1 = 0.f;
    if (ok) { a0 = src[0]; a1 = src[(size_t)8 * HW]; }
    __syncthreads();
    sA[tm * 32 + tn] = a0;
    sA[(tm + 8) * 32 + tn] = a1;
    {
      const float4* wt4 = (const float4*)(Wt + (size_t)k0 * 256);
      float4* sB4 = (float4*)sB;
#pragma unroll
      for (int t = 0; t < 4; t++) sB4[t * 256 + tid] = wt4[t * 256 + tid];
    }
    __syncthreads();
#pragma unroll
    for (int kk = 0; kk < 16; kk++) {
      float4 av = *(const float4*)&sA[kk * 32 + (tm << 2)];
      float4 b0 = *(const float4*)&sB[kk * 256 + (tn << 3)];
      float4 b1 = *(const float4*)&sB[kk * 256 + (tn << 3) + 4];
      float a4[4] = {av.x, av.y, av.z, av.w};
      float b8[8] = {b0.x, b0.y, b0.z, b0.w, b1.x, b1.y, b1.z, b1.w};
#pragma unroll
      for (int i = 0; i < 4; i++)
#pragma unroll
        for (int j = 0; j < 8; j++) acc[i][j] += a4[i] * b8[j];
    }
  }
  __syncthreads();
  // bias + relu -> sX
#pragma unroll
  for (int i = 0; i < 4; i++) {
    int m = (tm << 2) + i;
#pragma unroll
    for (int j = 0; j < 8; j++) {
      int co = (tn << 3) + j;
      float v = acc[i][j] + cb[co];
      sX[m * 257 + co] = v > 0.f ? v : 0.f;
    }
  }
  // 1x1 weights (3 cls + 12 box) into sB with stride 257 (bank-conflict pad)
  for (int t = tid; t < 15 * 256; t += 256) {
    int ch = t >> 8, ci = t & 255;
    sB[ch * 257 + ci] = (ch < 3) ? clsw[(ch << 8) + ci] : boxw[((ch - 3) << 8) + ci];
  }
  __syncthreads();
  // 32 pixels x 15 outputs
  for (int o = tid; o < 32 * 15; o += 256) {
    int m = o / 15;
    int ch = o - m * 15;
    const float* xr = &sX[m * 257];
    const float* wr = &sB[ch * 257];
    float s0 = 0.f, s1 = 0.f, s2 = 0.f, s3 = 0.f;
#pragma unroll 4
    for (int ci = 0; ci < 256; ci += 4) {
      s0 += xr[ci] * wr[ci];
      s1 += xr[ci + 1] * wr[ci + 1];
      s2 += xr[ci + 2] * wr[ci + 2];
      s3 += xr[ci + 3] * wr[ci + 3];
    }
    float s = (s0 + s1) + (s2 + s3);
    int gm = m0 + m;
    size_t aoff = (size_t)b * ATOT + lvloff + (size_t)gm * 3;
    if (ch < 3) {
      obj[aoff + ch] = s + clsb[ch];
    } else {
      int bc = ch - 3;
      delta[(aoff + (bc >> 2)) * 4 + (bc & 3)] = s + boxb[bc];
    }
  }
}

// ---------------------------------------------------------------- decode
__global__ __launch_bounds__(256) void decode_kernel(
    const float* __restrict__ obj, const float* __restrict__ delta,
    float* __restrict__ boxes, float* __restrict__ mscore) {
  int t = blockIdx.x * 256 + threadIdx.x;    // exact grid: NB*ATOT
  int b = t / ATOT;
  int a = t - b * ATOT;
  int off, hwsh, stsh;
  float size;
  if (a < 196608)       { off = 0;      hwsh = 8; stsh = 2; size = 32.f; }
  else if (a < 245760)  { off = 196608; hwsh = 7; stsh = 3; size = 64.f; }
  else if (a < 258048)  { off = 245760; hwsh = 6; stsh = 4; size = 128.f; }
  else if (a < 261120)  { off = 258048; hwsh = 5; stsh = 5; size = 256.f; }
  else                  { off = 261120; hwsh = 4; stsh = 6; size = 512.f; }
  int rel = a - off;
  int pix = rel / 3;
  int ar = rel - pix * 3;
  int y = pix >> hwsh;
  int x = pix & ((1 << hwsh) - 1);
  float ratio = (ar == 0) ? 0.5f : ((ar == 1) ? 1.0f : 2.0f);
  float sq = sqrtf(ratio);
  float hh = size * sq;          // matches np: size * sqrt(ratio)  (f32 ops)
  float wwv = size / sq;         // matches np: size / sqrt(ratio)
  float sx = (float)(x << stsh);
  float sy = (float)(y << stsh);
  float wh = wwv * 0.5f, hhh = hh * 0.5f;
  float a0 = sx - wh, a1 = sy - hhh, a2 = sx + wh, a3 = sy + hhh;
  float aw = a2 - a0, ah = a3 - a1;
  float ax = a0 + aw * 0.5f, ay = a1 + ah * 0.5f;
  const float* dp = delta + (size_t)t * 4;
  float dx = dp[0], dy = dp[1], dw = dp[2], dh = dp[3];
  float cx = dx * aw + ax;
  float cy = dy * ah + ay;
  float pw = expf(dw) * aw;
  float ph = expf(dh) * ah;
  float x1 = cx - pw * 0.5f, y1 = cy - ph * 0.5f;
  float x2 = cx + pw * 0.5f, y2 = cy + ph * 0.5f;
  x1 = fminf(fmaxf(x1, 0.f), 1024.f);
  y1 = fminf(fmaxf(y1, 0.f), 1024.f);
  x2 = fminf(fmaxf(x2, 0.f), 1024.f);
  y2 = fminf(fmaxf(y2, 0.f), 1024.f);
  float wsv = x2 - x1, hsv = y2 - y1;
  bool valid = (wsv >= 1.f) && (hsv >= 1.f);
  float o = obj[t];
  float sc = 1.f / (1.f + expf(-o));
  float* bp = boxes + (size_t)t * 4;
  bp[0] = x1; bp[1] = y1; bp[2] = x2; bp[3] = y2;
  mscore[t] = valid ? sc : -1e9f;
}

// ---------------------------------------------------------------- top-k (radix select)
__global__ __launch_bounds__(256) void hist1_kernel(const float* __restrict__ mscore,
                                                    u32* __restrict__ hist1) {
  int t = blockIdx.x * 256 + threadIdx.x;
  int b = t / ATOT;
  u32 u = sortable(mscore[t]);
  atomicAdd(&hist1[b * 65536 + (u >> 16)], 1u);
}

__global__ __launch_bounds__(256) void scan_hist(const u32* __restrict__ hist,
                                                 u32* __restrict__ info, int mode) {
  int b = blockIdx.x;
  const u32* h = hist + b * 65536;
  u32* inf = info + b * 16;
  __shared__ u32 partial[256];
  int tid = threadIdx.x;
  u32 s = 0;
  for (int i = 0; i < 256; i++) s += h[tid * 256 + i];
  partial[tid] = s;
  __syncthreads();
  if (tid == 0) {
    u32 K = (mode == 0) ? (u32)PRE_NMS_K : ((u32)PRE_NMS_K - inf[1]);
    u32 c = 0;
    int tstar = 0;
    for (int t = 255; t >= 0; t--) {
      if (c + partial[t] >= K) { tstar = t; break; }
      c += partial[t];
    }
    int bstar = tstar * 256;
    for (int bin = tstar * 256 + 255; bin >= tstar * 256; bin--) {
      u32 hv = h[bin];
      if (c + hv >= K) { bstar = bin; break; }
      c += hv;
    }
    if (mode == 0) { inf[0] = (u32)bstar; inf[1] = c; }
    else           { inf[2] = (u32)bstar; inf[3] = c; inf[4] = K - c; }
  }
}

__global__ __launch_bounds__(256) void hist2_kernel(const float* __restrict__ mscore,
                                                    const u32* __restrict__ info,
                                                    u32* __restrict__ hist2) {
  int t = blockIdx.x * 256 + threadIdx.x;
  int b = t / ATOT;
  u32 u = sortable(mscore[t]);
  if ((u >> 16) == info[b * 16]) atomicAdd(&hist2[b * 65536 + (u & 0xFFFFu)], 1u);
}

__global__ __launch_bounds__(256) void collect_kernel(
    const float* __restrict__ mscore, const u32* __restrict__ info,
    u32* __restrict__ sel_u, u32* __restrict__ sel_i, u32* __restrict__ eq_i,
    u32* __restrict__ cnts) {
  int t = blockIdx.x * 256 + threadIdx.x;
  int b = t / ATOT;
  int a = t - b * ATOT;
  const u32* inf = info + b * 16;
  u32 ustar = (inf[0] << 16) | inf[2];
  u32 u = sortable(mscore[t]);
  if (u > ustar) {
    u32 p = atomicAdd(&cnts[b], 1u);
    if (p < 1024u) { sel_u[b * 1024 + p] = u; sel_i[b * 1024 + p] = (u32)a; }
  } else if (u == ustar) {
    u32 p = atomicAdd(&cnts[2 + b], 1u);
    if (p < 4096u) eq_i[b * 4096 + p] = (u32)a;
  }
}

// sort equals by index asc (tie-break = lower index, matching lax.top_k),
// append, then bitonic-sort the 1000 by (score desc, idx asc); gather boxes.
__global__ __launch_bounds__(1024) void finalize_topk(
    const float* __restrict__ boxes, const float* __restrict__ mscore,
    const u32* __restrict__ info, const u32* __restrict__ sel_u,
    const u32* __restrict__ sel_i, const u32* __restrict__ eq_i,
    const u32* __restrict__ cnts, float* __restrict__ tb, float* __restrict__ ts) {
  int b = blockIdx.x, tid = threadIdx.x;
  const u32* inf = info + b * 16;
  u32 nsel = cnts[b];       if (nsel > 1000u) nsel = 1000u;
  u32 neq = cnts[2 + b];    if (neq > 4096u) neq = 4096u;
  u32 take = inf[4];        if (take > 1000u) take = 1000u;
  u32 ustar = (inf[0] << 16) | inf[2];
  u32 tot = nsel + take;    if (tot > 1024u) tot = 1024u;

  __shared__ u32 eqbuf[4096];
  __shared__ u64 keys[1024];
  for (int i = tid; i < 4096; i += 1024) eqbuf[i] = (i < (int)neq) ? eq_i[b * 4096 + i] : 0xFFFFFFFFu;
  __syncthreads();
  // ascending bitonic sort of eq indices
  for (int k = 2; k <= 4096; k <<= 1)
    for (int j = k >> 1; j > 0; j >>= 1) {
      for (int i = tid; i < 4096; i += 1024) {
        int p = i ^ j;
        if (p > i) {
          u32 x = eqbuf[i], y = eqbuf[p];
          bool up = ((i & k) == 0);
          if (up ? (x > y) : (x < y)) { eqbuf[i] = y; eqbuf[p] = x; }
        }
      }
      __syncthreads();
    }
  // build composite keys: (u desc, idx asc)
  u64 kv = 0;
  if (tid < (int)nsel) kv = ((u64)sel_u[b * 1024 + tid] << 32) | (u64)(0xFFFFFFFFu - sel_i[b * 1024 + tid]);
  else if (tid < (int)tot) kv = ((u64)ustar << 32) | (u64)(0xFFFFFFFFu - eqbuf[tid - nsel]);
  keys[tid] = kv;
  __syncthreads();
  // descending bitonic sort, 1024 elems / 1024 threads
  for (int k = 2; k <= 1024; k <<= 1)
    for (int j = k >> 1; j > 0; j >>= 1) {
      int p = tid ^ j;
      if (p > tid) {
        u64 x = keys[tid], y = keys[p];
        bool up = ((tid & k) == 0);
        if (up ? (x < y) : (x > y)) { keys[tid] = y; keys[p] = x; }
      }
      __syncthreads();
    }
  if (tid < PRE_NMS_K) {
    u32 idx = 0xFFFFFFFFu - (u32)(keys[tid] & 0xFFFFFFFFull);
    size_t g = (size_t)b * ATOT + idx;
    float4 bx = *(const float4*)(boxes + g * 4);
    *(float4*)(tb + (size_t)(b * PRE_NMS_K + tid) * 4) = bx;
    ts[b * PRE_NMS_K + tid] = mscore[g];
  }
}

// ---------------------------------------------------------------- NMS
__global__ __launch_bounds__(256) void nms_mask(const float* __restrict__ tb,
                                                u64* __restrict__ masks) {
  int t = blockIdx.x * 256 + threadIdx.x;   // 1000*16 per batch
  int b = blockIdx.y;
  if (t >= 16000) return;
  int i = t >> 4, w = t & 15;
  const float* B = tb + (size_t)b * 4000;
  float x1 = B[i * 4], y1 = B[i * 4 + 1], x2 = B[i * 4 + 2], y2 = B[i * 4 + 3];
  float ai = (x2 - x1) * (y2 - y1);
  u64 m = 0;
  int j0 = w << 6;
#pragma unroll 4
  for (int jj = 0; jj < 64; jj++) {
    int j = j0 + jj;
    if (j <= i || j >= 1000) continue;
    float bx1 = B[j * 4], by1 = B[j * 4 + 1], bx2 = B[j * 4 + 2], by2 = B[j * 4 + 3];
    float xx1 = fmaxf(x1, bx1), yy1 = fmaxf(y1, by1);
    float xx2 = fminf(x2, bx2), yy2 = fminf(y2, by2);
    float iw = fmaxf(xx2 - xx1, 0.f), ih = fmaxf(yy2 - yy1, 0.f);
    float inter = iw * ih;
    float aj = (bx2 - bx1) * (by2 - by1);
    float iou = inter / (ai + aj - inter + 1e-9f);
    if (iou > 0.7f) m |= (1ull << jj);
  }
  masks[((size_t)b * 1000 + i) * 16 + w] = m;
}

__global__ __launch_bounds__(64) void nms_scan(const float* __restrict__ tb,
                                               const float* __restrict__ ts,
                                               const u64* __restrict__ masks,
                                               float* __restrict__ out) {
  int b = blockIdx.x;
  int lane = threadIdx.x;   // 0..63, one wave
  u64 rem = 0;              // lanes 0..15 own removed-words
  __shared__ int keep[POST_NMS_K];
  __shared__ int kcount;
  if (lane == 0) kcount = 0;
  __syncthreads();
  const u64* M = masks + (size_t)b * 16000;
  for (int i = 0; i < 1000; i++) {
    int wi = i >> 6;
    u64 rw = __shfl(rem, wi);
    bool suppressed = (rw >> (i & 63)) & 1ull;
    if (!suppressed) {
      if (lane < 16) rem |= M[(size_t)i * 16 + lane];
      if (lane == 0) {
        if (ts[b * 1000 + i] > -100000000.0f && kcount < POST_NMS_K) {
          keep[kcount] = i;
          kcount++;
        }
      }
    }
  }
  __syncthreads();
  int kc = kcount;
  for (int r = lane; r < POST_NMS_K; r += 64) {
    float v0 = 0.f, v1 = 0.f, v2 = 0.f, v3 = 0.f, v4 = 0.f;
    if (r < kc) {
      int i = keep[r];
      const float* bp = tb + (size_t)(b * 1000 + i) * 4;
      v0 = bp[0]; v1 = bp[1]; v2 = bp[2]; v3 = bp[3];
      v4 = ts[b * 1000 + i];
    }
    float* op = out + (size_t)(b * POST_NMS_K + r) * 5;
    op[0] = v0; op[1] = v1; op[2] = v2; op[3] = v3; op[4] = v4;
  }
}

// ---------------------------------------------------------------- launch
extern "C" void kernel_launch(void* const* d_in, const int* in_sizes, int n_in,
                              void* d_out, int out_size, void* d_ws, size_t ws_size,
                              hipStream_t stream) {
  const float* feats[NLEV];
  for (int i = 0; i < NLEV; i++) feats[i] = (const float*)d_in[i];
  const float* conv_w = (const float*)d_in[5];
  const float* conv_b = (const float*)d_in[6];
  const float* cls_w  = (const float*)d_in[7];
  const float* cls_b  = (const float*)d_in[8];
  const float* box_w  = (const float*)d_in[9];
  const float* box_b  = (const float*)d_in[10];

  char* ws = (char*)d_ws;
  size_t off = 0;
  auto al = [&](size_t bytes) { size_t r = off; off = (off + bytes + 255) & ~(size_t)255; return r; };

  size_t o_Wt    = al((size_t)2304 * 256 * 4);
  size_t o_obj   = al((size_t)NB * ATOT * 4);
  size_t o_delta = al((size_t)NB * ATOT * 4 * 4);
  size_t o_boxes = al((size_t)NB * ATOT * 4 * 4);
  size_t o_msc   = al((size_t)NB * ATOT * 4);
  size_t o_zero  = al((size_t)(2 * 65536 + 2 * 65536 + 4) * 4);  // hist1|hist2|cnts
  size_t o_info  = al((size_t)NB * 16 * 4);
  size_t o_selu  = al((size_t)NB * 1024 * 4);
  size_t o_seli  = al((size_t)NB * 1024 * 4);
  size_t o_eqi   = al((size_t)NB * 4096 * 4);
  size_t o_tb    = al((size_t)NB * 1000 * 4 * 4);
  size_t o_ts    = al((size_t)NB * 1000 * 4);
  size_t o_mask  = al((size_t)NB * 1000 * 16 * 8);
  if (off > ws_size) return;  // workspace too small: fail loudly

  float* Wt    = (float*)(ws + o_Wt);
  float* obj   = (float*)(ws + o_obj);
  float* delta = (float*)(ws + o_delta);
  float* boxes = (float*)(ws + o_boxes);
  float* msc   = (float*)(ws + o_msc);
  u32* hist1   = (u32*)(ws + o_zero);
  u32* hist2   = hist1 + 2 * 65536;
  u32* cnts    = hist2 + 2 * 65536;
  u32* info    = (u32*)(ws + o_info);
  u32* sel_u   = (u32*)(ws + o_selu);
  u32* sel_i   = (u32*)(ws + o_seli);
  u32* eq_i    = (u32*)(ws + o_eqi);
  float* tb    = (float*)(ws + o_tb);
  float* ts    = (float*)(ws + o_ts);
  u64* masks   = (u64*)(ws + o_mask);
  float* out   = (float*)d_out;

  hipMemsetAsync(ws + o_zero, 0, (size_t)(2 * 65536 + 2 * 65536 + 4) * 4, stream);

  wt_kernel<<<2304, 256, 0, stream>>>(conv_w, Wt);

  const int hw[NLEV] = {256, 128, 64, 32, 16};
  const int aoff[NLEV] = {0, 196608, 245760, 258048, 261120};
  for (int l = 0; l < NLEV; l++) {
    dim3 grid(hw[l] * hw[l] / 32, NB);
    conv_fused<<<grid, 256, 0, stream>>>(feats[l], Wt, conv_b, cls_w, cls_b,
                                         box_w, box_b, obj, delta, hw[l], aoff[l]);
  }

  int ngrid = NB * ATOT / 256;  // 2046 exact
  decode_kernel<<<ngrid, 256, 0, stream>>>(obj, delta, boxes, msc);
  hist1_kernel<<<ngrid, 256, 0, stream>>>(msc, hist1);
  scan_hist<<<NB, 256, 0, stream>>>(hist1, info, 0);
  hist2_kernel<<<ngrid, 256, 0, stream>>>(msc, info, hist2);
  scan_hist<<<NB, 256, 0, stream>>>(hist2, info, 1);
  collect_kernel<<<ngrid, 256, 0, stream>>>(msc, info, sel_u, sel_i, eq_i, cnts);
  finalize_topk<<<NB, 1024, 0, stream>>>(boxes, msc, info, sel_u, sel_i, eq_i, cnts, tb, ts);
  nms_mask<<<dim3(63, NB), 256, 0, stream>>>(tb, masks);
  nms_scan<<<NB, 64, 0, stream>>>(tb, ts, masks, out);
}

// Round 2
// 2995.861 us; speedup vs baseline: 1.8230x; 1.8230x over previous
//
#include <hip/hip_runtime.h>
#include <math.h>

typedef unsigned int u32;
typedef unsigned long long u64;
typedef __attribute__((ext_vector_type(8))) short bf16x8;
typedef __attribute__((ext_vector_type(4))) float f32x4;

#define NLEV 5
#define ATOT 261888
#define NB 2
#define PRE_NMS_K 1000
#define POST_NMS_K 300

#define GLOBAL_AS __attribute__((address_space(1)))
#define LDS_AS __attribute__((address_space(3)))

__device__ __forceinline__ u32 sortable(float f) {
  u32 s = __float_as_uint(f);
  return (s & 0x80000000u) ? ~s : (s | 0x80000000u);
}

__device__ __forceinline__ unsigned short f2bf(float f) {
  u32 u = __float_as_uint(f);
  u32 r = (u + 0x7FFFu + ((u >> 16) & 1u)) >> 16;   // round-to-nearest-even
  return (unsigned short)r;
}
__device__ __forceinline__ float bf2f(unsigned short h) {
  return __uint_as_float(((u32)h) << 16);
}

// ---------------------------------------------------------------- weight split
// Wb: [3 splits][co=256][k=2304], k = r*256+ci, r = ky*3+kx (cross-correlation)
__global__ __launch_bounds__(256) void wt_split(const float* __restrict__ w,
                                                unsigned short* __restrict__ Wb) {
  int t = blockIdx.x * 256 + threadIdx.x;   // 256*2304 total
  int k = t % 2304;
  int co = t / 2304;
  int r = k >> 8, ci = k & 255;
  int ky = r / 3, kx = r - ky * 3;
  float v = w[(((co << 8) + ci) * 3 + ky) * 3 + kx];
  unsigned short s0 = f2bf(v);            float f0 = bf2f(s0);
  unsigned short s1 = f2bf(v - f0);       float f1 = bf2f(s1);
  unsigned short s2 = f2bf(v - f0 - f1);
  Wb[t] = s0;
  Wb[589824 + t] = s1;
  Wb[2 * 589824 + t] = s2;
}

// ---------------------------------------------------------------- halo zero
// Fb (as u32 pairs): [3][NB][PP][128]; zero the padded border pixels.
__global__ __launch_bounds__(256) void halo_zero(u32* __restrict__ Fb, int W, int PP, int H) {
  int t = blockIdx.x * 256 + threadIdx.x;
  int total = 3 * NB * H * 128;
  if (t >= total) return;
  int c = t & 127; int u = t >> 7;
  int hp = u % H; u /= H;
  int b = u % NB; int s = u / NB;
  int W2 = W + 2;
  int y, x;
  if (hp < 2 * W2) { y = (hp < W2) ? 0 : (W + 1); x = hp % W2; }
  else { int q = hp - 2 * W2; y = (q % W) + 1; x = (q < W) ? 0 : (W + 1); }
  size_t pidx = (size_t)y * W2 + x;
  Fb[(((size_t)s * NB + b) * PP + pidx) * 128 + c] = 0;
}

// ---------------------------------------------------------------- feature split
// NCHW fp32 -> NHWC-padded bf16 x3 splits. Fb: [3][NB][PP][256] ushort.
__global__ __launch_bounds__(256) void feat_split(const float* __restrict__ in,
                                                  unsigned short* __restrict__ Fb,
                                                  int W, int HW, int PP) {
  int b = blockIdx.y;
  int pix0 = blockIdx.x * 32;
  int tid = threadIdx.x;
  __shared__ float sT[32 * 257];
  const float* inb = in + (size_t)b * 256 * HW;
#pragma unroll 4
  for (int i = 0; i < 32; i++) {
    int idx = i * 256 + tid;
    int ci = idx >> 5;
    int px = idx & 31;
    sT[px * 257 + ci] = inb[(size_t)ci * HW + pix0 + px];
  }
  __syncthreads();
  size_t SplitSz = (size_t)NB * PP * 256;
  int W2 = W + 2;
#pragma unroll 4
  for (int i = 0; i < 32; i++) {
    float v = sT[i * 257 + tid];
    unsigned short s0 = f2bf(v);            float f0 = bf2f(s0);
    unsigned short s1 = f2bf(v - f0);       float f1 = bf2f(s1);
    unsigned short s2 = f2bf(v - f0 - f1);
    int pix = pix0 + i;
    int y = pix / W; int x = pix - y * W;
    size_t o = ((size_t)b * PP + (size_t)(y + 1) * W2 + (x + 1)) * 256 + tid;
    Fb[o] = s0; Fb[SplitSz + o] = s1; Fb[2 * SplitSz + o] = s2;
  }
}

// ---------------------------------------------------------------- MFMA conv
// C[m=pixel][n=cout] = sum_k A[m][k] B[k][n], K = 9 taps x 256 ci.
// 3-way bf16 splits both sides, 6 product MFMAs -> fp32-grade precision.
// Block: 128 pixels x 128 couts, 256 thr (4 waves of 64x64).
__global__ __launch_bounds__(256) void conv_mfma(
    const unsigned short* __restrict__ Fb,   // [3][NB][PP][256]
    const unsigned short* __restrict__ Wb,   // [3][256][2304]
    const float* __restrict__ cb,
    float* __restrict__ X,                   // [NB][HW][256] fp32 (relu'd)
    int W, int HW, int PP) {
  int b = blockIdx.z;
  int n0 = blockIdx.y * 128;
  int m0 = blockIdx.x * 128;
  int tid = threadIdx.x;
  int lane = tid & 63;
  int wv = tid >> 6;
  int wm = wv & 1, wn = wv >> 1;
  int W2 = W + 2;

  __shared__ __align__(16) unsigned short sA[3][128 * 32];
  __shared__ __align__(16) unsigned short sB[3][128 * 32];

  size_t SplitSz = (size_t)NB * PP * 256;
  int q = tid >> 2;              // 0..63
  int cisub = (tid & 3) * 8;

  long long aBase[2], bBase[2];
#pragma unroll
  for (int i = 0; i < 2; i++) {
    int p = m0 + q + 64 * i;
    int y = p / W; int x = p - y * W;
    aBase[i] = ((long long)b * PP + (long long)(y + 1) * W2 + (x + 1)) * 256 + cisub;
    int co = n0 + q + 64 * i;
    bBase[i] = (long long)co * 2304 + cisub;
  }

  int aoff[4], boff[4];
#pragma unroll
  for (int t4 = 0; t4 < 4; t4++) {
    aoff[t4] = (wm * 64 + t4 * 16 + (lane & 15)) * 32 + (lane >> 4) * 8;
    boff[t4] = (wn * 64 + t4 * 16 + (lane & 15)) * 32 + (lane >> 4) * 8;
  }

  f32x4 acc[4][4];
#pragma unroll
  for (int mt = 0; mt < 4; mt++)
#pragma unroll
    for (int nt = 0; nt < 4; nt++) acc[mt][nt] = (f32x4){0.f, 0.f, 0.f, 0.f};

  for (int kt = 0; kt < 72; kt++) {
    int r = kt >> 3;
    int ci0 = (kt & 7) * 32;
    int rdy = r / 3;
    long long dOff = (long long)(rdy - 1) * W2 + (r - rdy * 3 - 1);
    long long aIt = dOff * 256 + ci0;
    long long bIt = (long long)kt * 32;
    __syncthreads();
#pragma unroll
    for (int s = 0; s < 3; s++) {
      const unsigned short* As = Fb + (size_t)s * SplitSz;
      const unsigned short* Bs = Wb + (size_t)s * 589824;
#pragma unroll
      for (int i = 0; i < 2; i++) {
        __builtin_amdgcn_global_load_lds(
            (const GLOBAL_AS u32*)(As + aBase[i] + aIt),
            (LDS_AS u32*)((char*)&sA[s][0] + 4096 * i + 1024 * wv), 16, 0, 0);
        __builtin_amdgcn_global_load_lds(
            (const GLOBAL_AS u32*)(Bs + bBase[i] + bIt),
            (LDS_AS u32*)((char*)&sB[s][0] + 4096 * i + 1024 * wv), 16, 0, 0);
      }
    }
    __syncthreads();
    bf16x8 af[3][4];
#pragma unroll
    for (int s = 0; s < 3; s++)
#pragma unroll
      for (int mt = 0; mt < 4; mt++) af[s][mt] = *(const bf16x8*)&sA[s][aoff[mt]];
#pragma unroll
    for (int nt = 0; nt < 4; nt++) {
      bf16x8 b0 = *(const bf16x8*)&sB[0][boff[nt]];
      bf16x8 b1 = *(const bf16x8*)&sB[1][boff[nt]];
      bf16x8 b2 = *(const bf16x8*)&sB[2][boff[nt]];
#pragma unroll
      for (int mt = 0; mt < 4; mt++) {
        f32x4 c = acc[mt][nt];
        c = __builtin_amdgcn_mfma_f32_16x16x32_bf16(af[0][mt], b0, c, 0, 0, 0);
        c = __builtin_amdgcn_mfma_f32_16x16x32_bf16(af[0][mt], b1, c, 0, 0, 0);
        c = __builtin_amdgcn_mfma_f32_16x16x32_bf16(af[1][mt], b0, c, 0, 0, 0);
        c = __builtin_amdgcn_mfma_f32_16x16x32_bf16(af[0][mt], b2, c, 0, 0, 0);
        c = __builtin_amdgcn_mfma_f32_16x16x32_bf16(af[1][mt], b1, c, 0, 0, 0);
        c = __builtin_amdgcn_mfma_f32_16x16x32_bf16(af[2][mt], b0, c, 0, 0, 0);
        acc[mt][nt] = c;
      }
    }
  }
  // bias + relu + store (C/D layout: col=lane&15, row=(lane>>4)*4+reg)
  float* Xb = X + (size_t)b * HW * 256;
#pragma unroll
  for (int nt = 0; nt < 4; nt++) {
    int ch = n0 + wn * 64 + nt * 16 + (lane & 15);
    float bias = cb[ch];
#pragma unroll
    for (int mt = 0; mt < 4; mt++) {
      int mb = m0 + wm * 64 + mt * 16 + (lane >> 4) * 4;
      f32x4 c = acc[mt][nt];
#pragma unroll
      for (int rr = 0; rr < 4; rr++) {
        float v = c[rr] + bias;
        Xb[(size_t)(mb + rr) * 256 + ch] = v > 0.f ? v : 0.f;
      }
    }
  }
}

// ---------------------------------------------------------------- 1x1 epilogue
__global__ __launch_bounds__(256) void epilogue_1x1(
    const float* __restrict__ X, const float* __restrict__ clsw,
    const float* __restrict__ clsb, const float* __restrict__ boxw,
    const float* __restrict__ boxb, float* __restrict__ obj,
    float* __restrict__ delta, int HW, int lvloff) {
  int b = blockIdx.y;
  int pix0 = blockIdx.x * 32;
  int tid = threadIdx.x;
  __shared__ float sX[32 * 257];
  __shared__ float sW[15 * 257];
  const float* Xb = X + ((size_t)b * HW + pix0) * 256;
  for (int i = tid; i < 32 * 256; i += 256) {
    int p = i >> 8, ch = i & 255;
    sX[p * 257 + ch] = Xb[(size_t)p * 256 + ch];
  }
  for (int t = tid; t < 15 * 256; t += 256) {
    int ch = t >> 8, ci = t & 255;
    sW[ch * 257 + ci] = (ch < 3) ? clsw[(ch << 8) + ci] : boxw[((ch - 3) << 8) + ci];
  }
  __syncthreads();
  for (int o = tid; o < 32 * 15; o += 256) {
    int m = o / 15;
    int ch = o - m * 15;
    const float* xr = &sX[m * 257];
    const float* wr = &sW[ch * 257];
    float s0 = 0.f, s1 = 0.f, s2 = 0.f, s3 = 0.f;
#pragma unroll 4
    for (int ci = 0; ci < 256; ci += 4) {
      s0 += xr[ci] * wr[ci];
      s1 += xr[ci + 1] * wr[ci + 1];
      s2 += xr[ci + 2] * wr[ci + 2];
      s3 += xr[ci + 3] * wr[ci + 3];
    }
    float s = (s0 + s1) + (s2 + s3);
    int gm = pix0 + m;
    size_t aoff = (size_t)b * ATOT + lvloff + (size_t)gm * 3;
    if (ch < 3) {
      obj[aoff + ch] = s + clsb[ch];
    } else {
      int bc = ch - 3;
      delta[(aoff + (bc >> 2)) * 4 + (bc & 3)] = s + boxb[bc];
    }
  }
}

// ---------------------------------------------------------------- decode
__global__ __launch_bounds__(256) void decode_kernel(
    const float* __restrict__ obj, const float* __restrict__ delta,
    float* __restrict__ boxes, float* __restrict__ mscore) {
  int t = blockIdx.x * 256 + threadIdx.x;
  int b = t / ATOT;
  int a = t - b * ATOT;
  int off, hwsh, stsh;
  float size;
  if (a < 196608)       { off = 0;      hwsh = 8; stsh = 2; size = 32.f; }
  else if (a < 245760)  { off = 196608; hwsh = 7; stsh = 3; size = 64.f; }
  else if (a < 258048)  { off = 245760; hwsh = 6; stsh = 4; size = 128.f; }
  else if (a < 261120)  { off = 258048; hwsh = 5; stsh = 5; size = 256.f; }
  else                  { off = 261120; hwsh = 4; stsh = 6; size = 512.f; }
  int rel = a - off;
  int pix = rel / 3;
  int ar = rel - pix * 3;
  int y = pix >> hwsh;
  int x = pix & ((1 << hwsh) - 1);
  float ratio = (ar == 0) ? 0.5f : ((ar == 1) ? 1.0f : 2.0f);
  float sq = sqrtf(ratio);
  float hh = size * sq;
  float wwv = size / sq;
  float sx = (float)(x << stsh);
  float sy = (float)(y << stsh);
  float wh = wwv * 0.5f, hhh = hh * 0.5f;
  float a0 = sx - wh, a1 = sy - hhh, a2 = sx + wh, a3 = sy + hhh;
  float aw = a2 - a0, ah = a3 - a1;
  float ax = a0 + aw * 0.5f, ay = a1 + ah * 0.5f;
  const float* dp = delta + (size_t)t * 4;
  float dx = dp[0], dy = dp[1], dw = dp[2], dh = dp[3];
  float cx = dx * aw + ax;
  float cy = dy * ah + ay;
  float pw = expf(dw) * aw;
  float ph = expf(dh) * ah;
  float x1 = cx - pw * 0.5f, y1 = cy - ph * 0.5f;
  float x2 = cx + pw * 0.5f, y2 = cy + ph * 0.5f;
  x1 = fminf(fmaxf(x1, 0.f), 1024.f);
  y1 = fminf(fmaxf(y1, 0.f), 1024.f);
  x2 = fminf(fmaxf(x2, 0.f), 1024.f);
  y2 = fminf(fmaxf(y2, 0.f), 1024.f);
  float wsv = x2 - x1, hsv = y2 - y1;
  bool valid = (wsv >= 1.f) && (hsv >= 1.f);
  float o = obj[t];
  float sc = 1.f / (1.f + expf(-o));
  float* bp = boxes + (size_t)t * 4;
  bp[0] = x1; bp[1] = y1; bp[2] = x2; bp[3] = y2;
  mscore[t] = valid ? sc : -1e9f;
}

// ---------------------------------------------------------------- top-k (radix select)
__global__ __launch_bounds__(256) void hist1_kernel(const float* __restrict__ mscore,
                                                    u32* __restrict__ hist1) {
  int t = blockIdx.x * 256 + threadIdx.x;
  int b = t / ATOT;
  u32 u = sortable(mscore[t]);
  atomicAdd(&hist1[b * 65536 + (u >> 16)], 1u);
}

__global__ __launch_bounds__(256) void scan_hist(const u32* __restrict__ hist,
                                                 u32* __restrict__ info, int mode) {
  int b = blockIdx.x;
  const u32* h = hist + b * 65536;
  u32* inf = info + b * 16;
  __shared__ u32 partial[256];
  __shared__ u32 bins[256];
  __shared__ int sh_t;
  __shared__ u32 sh_c;
  int tid = threadIdx.x;
  u32 s = 0;
  for (int i = 0; i < 256; i++) s += h[tid * 256 + i];
  partial[tid] = s;
  __syncthreads();
  if (tid == 0) {
    u32 K = (mode == 0) ? (u32)PRE_NMS_K : ((u32)PRE_NMS_K - inf[1]);
    u32 c = 0;
    int tstar = 0;
    for (int t = 255; t >= 0; t--) {
      if (c + partial[t] >= K) { tstar = t; break; }
      c += partial[t];
    }
    sh_t = tstar; sh_c = c;
  }
  __syncthreads();
  bins[tid] = h[sh_t * 256 + tid];
  __syncthreads();
  if (tid == 0) {
    u32 K = (mode == 0) ? (u32)PRE_NMS_K : ((u32)PRE_NMS_K - inf[1]);
    u32 c = sh_c;
    int bstar = sh_t * 256;
    for (int j = 255; j >= 0; j--) {
      u32 hv = bins[j];
      if (c + hv >= K) { bstar = sh_t * 256 + j; break; }
      c += hv;
    }
    if (mode == 0) { inf[0] = (u32)bstar; inf[1] = c; }
    else           { inf[2] = (u32)bstar; inf[3] = c; inf[4] = K - c; }
  }
}

__global__ __launch_bounds__(256) void hist2_kernel(const float* __restrict__ mscore,
                                                    const u32* __restrict__ info,
                                                    u32* __restrict__ hist2) {
  int t = blockIdx.x * 256 + threadIdx.x;
  int b = t / ATOT;
  u32 u = sortable(mscore[t]);
  if ((u >> 16) == info[b * 16]) atomicAdd(&hist2[b * 65536 + (u & 0xFFFFu)], 1u);
}

__global__ __launch_bounds__(256) void collect_kernel(
    const float* __restrict__ mscore, const u32* __restrict__ info,
    u32* __restrict__ sel_u, u32* __restrict__ sel_i, u32* __restrict__ eq_i,
    u32* __restrict__ cnts) {
  int t = blockIdx.x * 256 + threadIdx.x;
  int b = t / ATOT;
  int a = t - b * ATOT;
  const u32* inf = info + b * 16;
  u32 ustar = (inf[0] << 16) | inf[2];
  u32 u = sortable(mscore[t]);
  if (u > ustar) {
    u32 p = atomicAdd(&cnts[b], 1u);
    if (p < 1024u) { sel_u[b * 1024 + p] = u; sel_i[b * 1024 + p] = (u32)a; }
  } else if (u == ustar) {
    u32 p = atomicAdd(&cnts[2 + b], 1u);
    if (p < 4096u) eq_i[b * 4096 + p] = (u32)a;
  }
}

__global__ __launch_bounds__(1024) void finalize_topk(
    const float* __restrict__ boxes, const float* __restrict__ mscore,
    const u32* __restrict__ info, const u32* __restrict__ sel_u,
    const u32* __restrict__ sel_i, const u32* __restrict__ eq_i,
    const u32* __restrict__ cnts, float* __restrict__ tb, float* __restrict__ ts) {
  int b = blockIdx.x, tid = threadIdx.x;
  const u32* inf = info + b * 16;
  u32 nsel = cnts[b];       if (nsel > 1000u) nsel = 1000u;
  u32 neq = cnts[2 + b];    if (neq > 4096u) neq = 4096u;
  u32 take = inf[4];        if (take > 1000u) take = 1000u;
  u32 ustar = (inf[0] << 16) | inf[2];
  u32 tot = nsel + take;    if (tot > 1024u) tot = 1024u;

  __shared__ u32 eqbuf[4096];
  __shared__ u64 keys[1024];
  for (int i = tid; i < 4096; i += 1024) eqbuf[i] = (i < (int)neq) ? eq_i[b * 4096 + i] : 0xFFFFFFFFu;
  __syncthreads();
  for (int k = 2; k <= 4096; k <<= 1)
    for (int j = k >> 1; j > 0; j >>= 1) {
      for (int i = tid; i < 4096; i += 1024) {
        int p = i ^ j;
        if (p > i) {
          u32 x = eqbuf[i], y = eqbuf[p];
          bool up = ((i & k) == 0);
          if (up ? (x > y) : (x < y)) { eqbuf[i] = y; eqbuf[p] = x; }
        }
      }
      __syncthreads();
    }
  u64 kv = 0;
  if (tid < (int)nsel) kv = ((u64)sel_u[b * 1024 + tid] << 32) | (u64)(0xFFFFFFFFu - sel_i[b * 1024 + tid]);
  else if (tid < (int)tot) kv = ((u64)ustar << 32) | (u64)(0xFFFFFFFFu - eqbuf[tid - nsel]);
  keys[tid] = kv;
  __syncthreads();
  for (int k = 2; k <= 1024; k <<= 1)
    for (int j = k >> 1; j > 0; j >>= 1) {
      int p = tid ^ j;
      if (p > tid) {
        u64 x = keys[tid], y = keys[p];
        bool up = ((tid & k) == 0);
        if (up ? (x < y) : (x > y)) { keys[tid] = y; keys[p] = x; }
      }
      __syncthreads();
    }
  if (tid < PRE_NMS_K) {
    u32 idx = 0xFFFFFFFFu - (u32)(keys[tid] & 0xFFFFFFFFull);
    size_t g = (size_t)b * ATOT + idx;
    float4 bx = *(const float4*)(boxes + g * 4);
    *(float4*)(tb + (size_t)(b * PRE_NMS_K + tid) * 4) = bx;
    ts[b * PRE_NMS_K + tid] = mscore[g];
  }
}

// ---------------------------------------------------------------- NMS
__global__ __launch_bounds__(256) void nms_mask(const float* __restrict__ tb,
                                                u64* __restrict__ masks) {
  int t = blockIdx.x * 256 + threadIdx.x;
  int b = blockIdx.y;
  if (t >= 16000) return;
  int i = t >> 4, w = t & 15;
  const float* B = tb + (size_t)b * 4000;
  float x1 = B[i * 4], y1 = B[i * 4 + 1], x2 = B[i * 4 + 2], y2 = B[i * 4 + 3];
  float ai = (x2 - x1) * (y2 - y1);
  u64 m = 0;
  int j0 = w << 6;
#pragma unroll 4
  for (int jj = 0; jj < 64; jj++) {
    int j = j0 + jj;
    if (j <= i || j >= 1000) continue;
    float bx1 = B[j * 4], by1 = B[j * 4 + 1], bx2 = B[j * 4 + 2], by2 = B[j * 4 + 3];
    float xx1 = fmaxf(x1, bx1), yy1 = fmaxf(y1, by1);
    float xx2 = fminf(x2, bx2), yy2 = fminf(y2, by2);
    float iw = fmaxf(xx2 - xx1, 0.f), ih = fmaxf(yy2 - yy1, 0.f);
    float inter = iw * ih;
    float aj = (bx2 - bx1) * (by2 - by1);
    float iou = inter / (ai + aj - inter + 1e-9f);
    if (iou > 0.7f) m |= (1ull << jj);
  }
  masks[((size_t)b * 1000 + i) * 16 + w] = m;
}

#define NMS_CHUNK 448
__global__ __launch_bounds__(256) void nms_scan(const float* __restrict__ tb,
                                                const float* __restrict__ ts,
                                                const u64* __restrict__ masks,
                                                float* __restrict__ out) {
  int b = blockIdx.x;
  int tid = threadIdx.x;
  int lane = tid & 63;
  __shared__ u64 mchunk[NMS_CHUNK * 16];
  __shared__ float sts[1000];
  __shared__ int keep[POST_NMS_K];
  __shared__ int kcount;
  for (int i = tid; i < 1000; i += 256) sts[i] = ts[b * 1000 + i];
  if (tid == 0) kcount = 0;
  u64 rem = 0;           // wave0 lanes 0..15 hold suppression words
  int kreg = 0;          // lane0's keep count
  const u64* M = masks + (size_t)b * 16000;
  for (int c0 = 0; c0 < 1000; c0 += NMS_CHUNK) {
    int cn = min(NMS_CHUNK, 1000 - c0);
    __syncthreads();
    if (kcount >= POST_NMS_K) break;
    for (int i = tid; i < cn * 16; i += 256) mchunk[i] = M[(size_t)c0 * 16 + i];
    __syncthreads();
    if (tid < 64) {
      for (int i = c0; i < c0 + cn; i++) {
        int kc_all = __shfl(kreg, 0);
        if (kc_all >= POST_NMS_K) break;
        u64 rw = __shfl(rem, i >> 6);
        bool sup = (rw >> (i & 63)) & 1ull;
        if (!sup) {
          if (lane < 16) rem |= mchunk[(i - c0) * 16 + lane];
          if (lane == 0 && sts[i] > -100000000.0f) { keep[kreg] = i; kreg++; }
        }
      }
      if (lane == 0) kcount = kreg;
    }
  }
  __syncthreads();
  int kc = kcount; if (kc > POST_NMS_K) kc = POST_NMS_K;
  for (int r = tid; r < POST_NMS_K; r += 256) {
    float v0 = 0.f, v1 = 0.f, v2 = 0.f, v3 = 0.f, v4 = 0.f;
    if (r < kc) {
      int i = keep[r];
      const float* bp = tb + (size_t)(b * 1000 + i) * 4;
      v0 = bp[0]; v1 = bp[1]; v2 = bp[2]; v3 = bp[3];
      v4 = sts[i];
    }
    float* op = out + (size_t)(b * POST_NMS_K + r) * 5;
    op[0] = v0; op[1] = v1; op[2] = v2; op[3] = v3; op[4] = v4;
  }
}

// ---------------------------------------------------------------- launch
extern "C" void kernel_launch(void* const* d_in, const int* in_sizes, int n_in,
                              void* d_out, int out_size, void* d_ws, size_t ws_size,
                              hipStream_t stream) {
  const float* feats[NLEV];
  for (int i = 0; i < NLEV; i++) feats[i] = (const float*)d_in[i];
  const float* conv_w = (const float*)d_in[5];
  const float* conv_b = (const float*)d_in[6];
  const float* cls_w  = (const float*)d_in[7];
  const float* cls_b  = (const float*)d_in[8];
  const float* box_w  = (const float*)d_in[9];
  const float* box_b  = (const float*)d_in[10];

  char* ws = (char*)d_ws;
  size_t off = 0;
  auto al = [&](size_t bytes) { size_t r = off; off = (off + bytes + 255) & ~(size_t)255; return r; };

  size_t o_Wb    = al((size_t)3 * 589824 * 2);
  size_t o_obj   = al((size_t)NB * ATOT * 4);
  size_t o_delta = al((size_t)NB * ATOT * 16);
  size_t o_boxes = al((size_t)NB * ATOT * 16);
  size_t o_msc   = al((size_t)NB * ATOT * 4);
  size_t o_zero  = al((size_t)(2 * 65536 + 2 * 65536 + 4) * 4);
  size_t o_info  = al((size_t)NB * 16 * 4);
  size_t o_selu  = al((size_t)NB * 1024 * 4);
  size_t o_seli  = al((size_t)NB * 1024 * 4);
  size_t o_eqi   = al((size_t)NB * 4096 * 4);
  size_t o_tb    = al((size_t)NB * 1000 * 16);
  size_t o_ts    = al((size_t)NB * 1000 * 4);
  size_t o_mask  = al((size_t)NB * 16000 * 8);
  size_t PPmax   = 258 * 258;
  size_t o_Fb    = al((size_t)3 * NB * PPmax * 256 * 2);   // ~204 MB (reused per level)
  size_t o_X     = al((size_t)NB * 65536 * 256 * 4);       // ~134 MB (reused per level)
  if (off > ws_size) return;  // fail loudly (output stays poisoned)

  unsigned short* Wb = (unsigned short*)(ws + o_Wb);
  float* obj   = (float*)(ws + o_obj);
  float* delta = (float*)(ws + o_delta);
  float* boxes = (float*)(ws + o_boxes);
  float* msc   = (float*)(ws + o_msc);
  u32* hist1   = (u32*)(ws + o_zero);
  u32* hist2   = hist1 + 2 * 65536;
  u32* cnts    = hist2 + 2 * 65536;
  u32* info    = (u32*)(ws + o_info);
  u32* sel_u   = (u32*)(ws + o_selu);
  u32* sel_i   = (u32*)(ws + o_seli);
  u32* eq_i    = (u32*)(ws + o_eqi);
  float* tb    = (float*)(ws + o_tb);
  float* ts    = (float*)(ws + o_ts);
  u64* masks   = (u64*)(ws + o_mask);
  unsigned short* Fb = (unsigned short*)(ws + o_Fb);
  float* X     = (float*)(ws + o_X);
  float* out   = (float*)d_out;

  hipMemsetAsync(ws + o_zero, 0, (size_t)(2 * 65536 + 2 * 65536 + 4) * 4, stream);

  wt_split<<<2304, 256, 0, stream>>>(conv_w, Wb);

  const int hw[NLEV] = {256, 128, 64, 32, 16};
  const int aoff[NLEV] = {0, 196608, 245760, 258048, 261120};
  for (int l = 0; l < NLEV; l++) {
    int W = hw[l], HW = W * W, PP = (W + 2) * (W + 2);
    int H = 2 * (W + 2) + 2 * W;
    int hz = 3 * NB * H * 128;
    halo_zero<<<(hz + 255) / 256, 256, 0, stream>>>((u32*)Fb, W, PP, H);
    feat_split<<<dim3(HW / 32, NB), 256, 0, stream>>>(feats[l], Fb, W, HW, PP);
    conv_mfma<<<dim3(HW / 128, 2, NB), 256, 0, stream>>>(Fb, Wb, conv_b, X, W, HW, PP);
    epilogue_1x1<<<dim3(HW / 32, NB), 256, 0, stream>>>(X, cls_w, cls_b, box_w, box_b,
                                                        obj, delta, HW, aoff[l]);
  }

  int ngrid = NB * ATOT / 256;
  decode_kernel<<<ngrid, 256, 0, stream>>>(obj, delta, boxes, msc);
  hist1_kernel<<<ngrid, 256, 0, stream>>>(msc, hist1);
  scan_hist<<<NB, 256, 0, stream>>>(hist1, info, 0);
  hist2_kernel<<<ngrid, 256, 0, stream>>>(msc, info, hist2);
  scan_hist<<<NB, 256, 0, stream>>>(hist2, info, 1);
  collect_kernel<<<ngrid, 256, 0, stream>>>(msc, info, sel_u, sel_i, eq_i, cnts);
  finalize_topk<<<NB, 1024, 0, stream>>>(boxes, msc, info, sel_u, sel_i, eq_i, cnts, tb, ts);
  nms_mask<<<dim3(63, NB), 256, 0, stream>>>(tb, masks);
  nms_scan<<<NB, 256, 0, stream>>>(tb, ts, masks, out);
}

// Round 3
// 2095.435 us; speedup vs baseline: 2.6064x; 1.4297x over previous
//
#include <hip/hip_runtime.h>
#include <math.h>

typedef unsigned int u32;
typedef unsigned long long u64;
typedef __attribute__((ext_vector_type(8))) _Float16 f16x8;
typedef __attribute__((ext_vector_type(4))) float f32x4;

#define NLEV 5
#define ATOT 261888
#define NB 2
#define PRE_NMS_K 1000
#define POST_NMS_K 300

#define GLOBAL_AS __attribute__((address_space(1)))
#define LDS_AS __attribute__((address_space(3)))

__device__ __forceinline__ u32 sortable(float f) {
  u32 s = __float_as_uint(f);
  return (s & 0x80000000u) ? ~s : (s | 0x80000000u);
}

// ---------------------------------------------------------------- weight split
// Wb: [2 splits][co=256][k=2304], k = r*256+ci, r = ky*3+kx.
// Split 1 is scaled by 2048 so the residual stays in f16 normal range.
__global__ __launch_bounds__(256) void wt_split(const float* __restrict__ w,
                                                _Float16* __restrict__ Wb) {
  int t = blockIdx.x * 256 + threadIdx.x;   // 256*2304 total
  int k = t % 2304;
  int co = t / 2304;
  int r = k >> 8, ci = k & 255;
  int ky = r / 3, kx = r - ky * 3;
  float v = w[(((co << 8) + ci) * 3 + ky) * 3 + kx];
  _Float16 s0 = (_Float16)v;
  _Float16 s1 = (_Float16)((v - (float)s0) * 2048.0f);
  Wb[t] = s0;
  Wb[589824 + t] = s1;
}

// ---------------------------------------------------------------- halo zero
__global__ __launch_bounds__(256) void halo_zero(u32* __restrict__ Fb, int W, int PP, int H) {
  int t = blockIdx.x * 256 + threadIdx.x;
  int total = 2 * NB * H * 128;
  if (t >= total) return;
  int c = t & 127; int u = t >> 7;
  int hp = u % H; u /= H;
  int b = u % NB; int s = u / NB;
  int W2 = W + 2;
  int y, x;
  if (hp < 2 * W2) { y = (hp < W2) ? 0 : (W + 1); x = hp % W2; }
  else { int q = hp - 2 * W2; y = (q % W) + 1; x = (q < W) ? 0 : (W + 1); }
  size_t pidx = (size_t)y * W2 + x;
  Fb[(((size_t)s * NB + b) * PP + pidx) * 128 + c] = 0;
}

// ---------------------------------------------------------------- feature split
// NCHW fp32 -> NHWC-padded f16 x2 splits (split1 scaled x2048).
__global__ __launch_bounds__(256) void feat_split(const float* __restrict__ in,
                                                  _Float16* __restrict__ Fb,
                                                  int W, int HW, int PP) {
  int b = blockIdx.y;
  int pix0 = blockIdx.x * 32;
  int tid = threadIdx.x;
  __shared__ float sT[32 * 257];
  const float* inb = in + (size_t)b * 256 * HW;
#pragma unroll 4
  for (int i = 0; i < 32; i++) {
    int idx = i * 256 + tid;
    int ci = idx >> 5;
    int px = idx & 31;
    sT[px * 257 + ci] = inb[(size_t)ci * HW + pix0 + px];
  }
  __syncthreads();
  size_t SplitSz = (size_t)NB * PP * 256;
  int W2 = W + 2;
#pragma unroll 4
  for (int i = 0; i < 32; i++) {
    float v = sT[i * 257 + tid];
    _Float16 s0 = (_Float16)v;
    _Float16 s1 = (_Float16)((v - (float)s0) * 2048.0f);
    int pix = pix0 + i;
    int y = pix / W; int x = pix - y * W;
    size_t o = ((size_t)b * PP + (size_t)(y + 1) * W2 + (x + 1)) * 256 + tid;
    Fb[o] = s0; Fb[SplitSz + o] = s1;
  }
}

// ---------------------------------------------------------------- MFMA conv
// f16 2-split, 3 products: acc1 = A0*W0 ; acc2 = A0*W1' + A1'*W0 (both x2048)
// result = acc1 + acc2/2048.  K-loop: ci-chunk OUTER, tap INNER (L2 tap reuse).
__global__ __launch_bounds__(256) void conv_mfma(
    const _Float16* __restrict__ Fb,   // [2][NB][PP][256]
    const _Float16* __restrict__ Wb,   // [2][256][2304]
    const float* __restrict__ cb,
    float* __restrict__ X,             // [NB][HW][256] fp32 (relu'd)
    int W, int HW, int PP) {
  int b = blockIdx.z;
  int n0 = blockIdx.y * 128;
  int m0 = blockIdx.x * 128;
  int tid = threadIdx.x;
  int lane = tid & 63;
  int wv = tid >> 6;
  int wm = wv & 1, wn = wv >> 1;
  int W2 = W + 2;

  __shared__ __align__(16) _Float16 sA[2][128 * 32];
  __shared__ __align__(16) _Float16 sB[2][128 * 32];

  size_t SplitSz = (size_t)NB * PP * 256;
  int q = tid >> 2;              // 0..63
  int cisub = (tid & 3) * 8;

  long long aBase[2], bBase[2];
#pragma unroll
  for (int i = 0; i < 2; i++) {
    int p = m0 + q + 64 * i;
    int y = p / W; int x = p - y * W;
    aBase[i] = ((long long)b * PP + (long long)(y + 1) * W2 + (x + 1)) * 256 + cisub;
    int co = n0 + q + 64 * i;
    bBase[i] = (long long)co * 2304 + cisub;
  }

  int aoff[4], boff[4];
#pragma unroll
  for (int t4 = 0; t4 < 4; t4++) {
    aoff[t4] = (wm * 64 + t4 * 16 + (lane & 15)) * 32 + (lane >> 4) * 8;
    boff[t4] = (wn * 64 + t4 * 16 + (lane & 15)) * 32 + (lane >> 4) * 8;
  }

  f32x4 acc1[4][4], acc2[4][4];
#pragma unroll
  for (int mt = 0; mt < 4; mt++)
#pragma unroll
    for (int nt = 0; nt < 4; nt++) {
      acc1[mt][nt] = (f32x4){0.f, 0.f, 0.f, 0.f};
      acc2[mt][nt] = (f32x4){0.f, 0.f, 0.f, 0.f};
    }

  for (int kt = 0; kt < 72; kt++) {
    int c = kt / 9;                 // ci-chunk (outer order)
    int r = kt - c * 9;             // tap (inner order -> L2 reuse)
    int rdy = r / 3;
    long long dOff = (long long)(rdy - 1) * W2 + (r - rdy * 3 - 1);
    long long aIt = dOff * 256 + c * 32;
    long long bIt = (long long)r * 256 + c * 32;
    __syncthreads();
#pragma unroll
    for (int s = 0; s < 2; s++) {
      const _Float16* As = Fb + (size_t)s * SplitSz;
      const _Float16* Bs = Wb + (size_t)s * 589824;
#pragma unroll
      for (int i = 0; i < 2; i++) {
        __builtin_amdgcn_global_load_lds(
            (const GLOBAL_AS u32*)(As + aBase[i] + aIt),
            (LDS_AS u32*)((char*)&sA[s][0] + 4096 * i + 1024 * wv), 16, 0, 0);
        __builtin_amdgcn_global_load_lds(
            (const GLOBAL_AS u32*)(Bs + bBase[i] + bIt),
            (LDS_AS u32*)((char*)&sB[s][0] + 4096 * i + 1024 * wv), 16, 0, 0);
      }
    }
    __syncthreads();
    f16x8 af0[4], af1[4];
#pragma unroll
    for (int mt = 0; mt < 4; mt++) {
      af0[mt] = *(const f16x8*)&sA[0][aoff[mt]];
      af1[mt] = *(const f16x8*)&sA[1][aoff[mt]];
    }
#pragma unroll
    for (int nt = 0; nt < 4; nt++) {
      f16x8 b0 = *(const f16x8*)&sB[0][boff[nt]];
      f16x8 b1 = *(const f16x8*)&sB[1][boff[nt]];
#pragma unroll
      for (int mt = 0; mt < 4; mt++) {
        acc1[mt][nt] = __builtin_amdgcn_mfma_f32_16x16x32_f16(af0[mt], b0, acc1[mt][nt], 0, 0, 0);
        acc2[mt][nt] = __builtin_amdgcn_mfma_f32_16x16x32_f16(af0[mt], b1, acc2[mt][nt], 0, 0, 0);
        acc2[mt][nt] = __builtin_amdgcn_mfma_f32_16x16x32_f16(af1[mt], b0, acc2[mt][nt], 0, 0, 0);
      }
    }
  }
  // combine + bias + relu + store (C/D layout: col=lane&15, row=(lane>>4)*4+reg)
  const float inv2048 = 1.0f / 2048.0f;
  float* Xb = X + (size_t)b * HW * 256;
#pragma unroll
  for (int nt = 0; nt < 4; nt++) {
    int ch = n0 + wn * 64 + nt * 16 + (lane & 15);
    float bias = cb[ch];
#pragma unroll
    for (int mt = 0; mt < 4; mt++) {
      int mb = m0 + wm * 64 + mt * 16 + (lane >> 4) * 4;
      f32x4 c1 = acc1[mt][nt];
      f32x4 c2 = acc2[mt][nt];
#pragma unroll
      for (int rr = 0; rr < 4; rr++) {
        float v = c1[rr] + c2[rr] * inv2048 + bias;
        Xb[(size_t)(mb + rr) * 256 + ch] = v > 0.f ? v : 0.f;
      }
    }
  }
}

// ---------------------------------------------------------------- 1x1 epilogue
__global__ __launch_bounds__(256) void epilogue_1x1(
    const float* __restrict__ X, const float* __restrict__ clsw,
    const float* __restrict__ clsb, const float* __restrict__ boxw,
    const float* __restrict__ boxb, float* __restrict__ obj,
    float* __restrict__ delta, int HW, int lvloff) {
  int b = blockIdx.y;
  int pix0 = blockIdx.x * 32;
  int tid = threadIdx.x;
  __shared__ float sX[32 * 257];
  __shared__ float sW[15 * 257];
  const float4* X4 = (const float4*)(X + ((size_t)b * HW + pix0) * 256);
  for (int i = tid; i < 32 * 64; i += 256) {
    int p = i >> 6, c4 = i & 63;
    float4 v = X4[p * 64 + c4];
    float* dst = &sX[p * 257 + c4 * 4];
    dst[0] = v.x; dst[1] = v.y; dst[2] = v.z; dst[3] = v.w;
  }
  for (int t = tid; t < 15 * 256; t += 256) {
    int ch = t >> 8, ci = t & 255;
    sW[ch * 257 + ci] = (ch < 3) ? clsw[(ch << 8) + ci] : boxw[((ch - 3) << 8) + ci];
  }
  __syncthreads();
  for (int o = tid; o < 32 * 15; o += 256) {
    int m = o / 15;
    int ch = o - m * 15;
    const float* xr = &sX[m * 257];
    const float* wr = &sW[ch * 257];
    float s0 = 0.f, s1 = 0.f, s2 = 0.f, s3 = 0.f;
#pragma unroll 4
    for (int ci = 0; ci < 256; ci += 4) {
      s0 += xr[ci] * wr[ci];
      s1 += xr[ci + 1] * wr[ci + 1];
      s2 += xr[ci + 2] * wr[ci + 2];
      s3 += xr[ci + 3] * wr[ci + 3];
    }
    float s = (s0 + s1) + (s2 + s3);
    int gm = pix0 + m;
    size_t aoff = (size_t)b * ATOT + lvloff + (size_t)gm * 3;
    if (ch < 3) {
      obj[aoff + ch] = s + clsb[ch];
    } else {
      int bc = ch - 3;
      delta[(aoff + (bc >> 2)) * 4 + (bc & 3)] = s + boxb[bc];
    }
  }
}

// ---------------------------------------------------------------- decode (+ radix pass 0)
__global__ __launch_bounds__(256) void decode_kernel(
    const float* __restrict__ obj, const float* __restrict__ delta,
    float* __restrict__ boxes, float* __restrict__ mscore,
    u32* __restrict__ gh0) {
  __shared__ u32 lh[256];
  int tid = threadIdx.x;
  lh[tid] = 0;
  __syncthreads();
  int t = blockIdx.x * 256 + tid;
  int b = t / ATOT;
  int a = t - b * ATOT;
  int off, hwsh, stsh;
  float size;
  if (a < 196608)       { off = 0;      hwsh = 8; stsh = 2; size = 32.f; }
  else if (a < 245760)  { off = 196608; hwsh = 7; stsh = 3; size = 64.f; }
  else if (a < 258048)  { off = 245760; hwsh = 6; stsh = 4; size = 128.f; }
  else if (a < 261120)  { off = 258048; hwsh = 5; stsh = 5; size = 256.f; }
  else                  { off = 261120; hwsh = 4; stsh = 6; size = 512.f; }
  int rel = a - off;
  int pix = rel / 3;
  int ar = rel - pix * 3;
  int y = pix >> hwsh;
  int x = pix & ((1 << hwsh) - 1);
  float ratio = (ar == 0) ? 0.5f : ((ar == 1) ? 1.0f : 2.0f);
  float sq = sqrtf(ratio);
  float hh = size * sq;
  float wwv = size / sq;
  float sx = (float)(x << stsh);
  float sy = (float)(y << stsh);
  float wh = wwv * 0.5f, hhh = hh * 0.5f;
  float a0 = sx - wh, a1 = sy - hhh, a2 = sx + wh, a3 = sy + hhh;
  float aw = a2 - a0, ah = a3 - a1;
  float ax = a0 + aw * 0.5f, ay = a1 + ah * 0.5f;
  const float* dp = delta + (size_t)t * 4;
  float dx = dp[0], dy = dp[1], dw = dp[2], dh = dp[3];
  float cx = dx * aw + ax;
  float cy = dy * ah + ay;
  float pw = expf(dw) * aw;
  float ph = expf(dh) * ah;
  float x1 = cx - pw * 0.5f, y1 = cy - ph * 0.5f;
  float x2 = cx + pw * 0.5f, y2 = cy + ph * 0.5f;
  x1 = fminf(fmaxf(x1, 0.f), 1024.f);
  y1 = fminf(fmaxf(y1, 0.f), 1024.f);
  x2 = fminf(fmaxf(x2, 0.f), 1024.f);
  y2 = fminf(fmaxf(y2, 0.f), 1024.f);
  float wsv = x2 - x1, hsv = y2 - y1;
  bool valid = (wsv >= 1.f) && (hsv >= 1.f);
  float o = obj[t];
  float sc = 1.f / (1.f + expf(-o));
  float ms = valid ? sc : -1e9f;
  float* bp = boxes + (size_t)t * 4;
  bp[0] = x1; bp[1] = y1; bp[2] = x2; bp[3] = y2;
  mscore[t] = ms;
  atomicAdd(&lh[sortable(ms) >> 24], 1u);
  __syncthreads();
  u32 v = lh[tid];
  if (v) atomicAdd(&gh0[b * 256 + tid], v);
}

// ---------------------------------------------------------------- radix passes 1..3
__global__ __launch_bounds__(256) void hist_pass(const float* __restrict__ mscore,
                                                 const u32* __restrict__ info,
                                                 u32* __restrict__ gh,
                                                 int pshift, int bshift) {
  __shared__ u32 lh[256];
  int tid = threadIdx.x;
  lh[tid] = 0;
  __syncthreads();
  int t = blockIdx.x * 256 + tid;
  int b = t / ATOT;
  u32 u = sortable(mscore[t]);
  if ((u >> pshift) == info[b * 16]) atomicAdd(&lh[(u >> bshift) & 255u], 1u);
  __syncthreads();
  u32 v = lh[tid];
  if (v) atomicAdd(&gh[b * 256 + tid], v);
}

__global__ __launch_bounds__(256) void scan8(const u32* __restrict__ gh,
                                             u32* __restrict__ info, int mode) {
  int b = blockIdx.x;
  int tid = threadIdx.x;
  __shared__ u32 h[256];
  h[tid] = gh[b * 256 + tid];
  __syncthreads();
  if (tid == 0) {
    u32* inf = &info[b * 16];
    u32 K = (u32)PRE_NMS_K - inf[1];
    u32 c = 0;
    int bstar = 0;
    for (int j = 255; j >= 0; j--) {
      u32 hv = h[j];
      if (c + hv >= K) { bstar = j; break; }
      c += hv;
    }
    inf[0] = (inf[0] << 8) | (u32)bstar;
    inf[1] += c;
    if (mode == 3) inf[4] = K - c;
  }
}

__global__ __launch_bounds__(256) void collect_kernel(
    const float* __restrict__ mscore, const u32* __restrict__ info,
    u32* __restrict__ sel_u, u32* __restrict__ sel_i, u32* __restrict__ eq_i,
    u32* __restrict__ cnts) {
  int t = blockIdx.x * 256 + threadIdx.x;
  int b = t / ATOT;
  int a = t - b * ATOT;
  u32 ustar = info[b * 16];
  u32 u = sortable(mscore[t]);
  if (u > ustar) {
    u32 p = atomicAdd(&cnts[b], 1u);
    if (p < 1024u) { sel_u[b * 1024 + p] = u; sel_i[b * 1024 + p] = (u32)a; }
  } else if (u == ustar) {
    u32 p = atomicAdd(&cnts[2 + b], 1u);
    if (p < 4096u) eq_i[b * 4096 + p] = (u32)a;
  }
}

__global__ __launch_bounds__(1024) void finalize_topk(
    const float* __restrict__ boxes, const float* __restrict__ mscore,
    const u32* __restrict__ info, const u32* __restrict__ sel_u,
    const u32* __restrict__ sel_i, const u32* __restrict__ eq_i,
    const u32* __restrict__ cnts, float* __restrict__ tb, float* __restrict__ ts) {
  int b = blockIdx.x, tid = threadIdx.x;
  const u32* inf = info + b * 16;
  u32 nsel = cnts[b];       if (nsel > 1000u) nsel = 1000u;
  u32 neq = cnts[2 + b];    if (neq > 4096u) neq = 4096u;
  u32 take = inf[4];        if (take > 1000u) take = 1000u;
  u32 ustar = inf[0];
  u32 tot = nsel + take;    if (tot > 1024u) tot = 1024u;

  __shared__ u32 eqbuf[4096];
  __shared__ u64 keys[1024];
  for (int i = tid; i < 4096; i += 1024) eqbuf[i] = (i < (int)neq) ? eq_i[b * 4096 + i] : 0xFFFFFFFFu;
  __syncthreads();
  for (int k = 2; k <= 4096; k <<= 1)
    for (int j = k >> 1; j > 0; j >>= 1) {
      for (int i = tid; i < 4096; i += 1024) {
        int p = i ^ j;
        if (p > i) {
          u32 x = eqbuf[i], y = eqbuf[p];
          bool up = ((i & k) == 0);
          if (up ? (x > y) : (x < y)) { eqbuf[i] = y; eqbuf[p] = x; }
        }
      }
      __syncthreads();
    }
  u64 kv = 0;
  if (tid < (int)nsel) kv = ((u64)sel_u[b * 1024 + tid] << 32) | (u64)(0xFFFFFFFFu - sel_i[b * 1024 + tid]);
  else if (tid < (int)tot) kv = ((u64)ustar << 32) | (u64)(0xFFFFFFFFu - eqbuf[tid - nsel]);
  keys[tid] = kv;
  __syncthreads();
  for (int k = 2; k <= 1024; k <<= 1)
    for (int j = k >> 1; j > 0; j >>= 1) {
      int p = tid ^ j;
      if (p > tid) {
        u64 x = keys[tid], y = keys[p];
        bool up = ((tid & k) == 0);
        if (up ? (x < y) : (x > y)) { keys[tid] = y; keys[p] = x; }
      }
      __syncthreads();
    }
  if (tid < PRE_NMS_K) {
    u32 idx = 0xFFFFFFFFu - (u32)(keys[tid] & 0xFFFFFFFFull);
    size_t g = (size_t)b * ATOT + idx;
    float4 bx = *(const float4*)(boxes + g * 4);
    *(float4*)(tb + (size_t)(b * PRE_NMS_K + tid) * 4) = bx;
    ts[b * PRE_NMS_K + tid] = mscore[g];
  }
}

// ---------------------------------------------------------------- NMS
__global__ __launch_bounds__(256) void nms_mask(const float* __restrict__ tb,
                                                u64* __restrict__ masks) {
  int t = blockIdx.x * 256 + threadIdx.x;
  int b = blockIdx.y;
  if (t >= 16000) return;
  int i = t >> 4, w = t & 15;
  const float* B = tb + (size_t)b * 4000;
  float x1 = B[i * 4], y1 = B[i * 4 + 1], x2 = B[i * 4 + 2], y2 = B[i * 4 + 3];
  float ai = (x2 - x1) * (y2 - y1);
  u64 m = 0;
  int j0 = w << 6;
#pragma unroll 4
  for (int jj = 0; jj < 64; jj++) {
    int j = j0 + jj;
    if (j <= i || j >= 1000) continue;
    float bx1 = B[j * 4], by1 = B[j * 4 + 1], bx2 = B[j * 4 + 2], by2 = B[j * 4 + 3];
    float xx1 = fmaxf(x1, bx1), yy1 = fmaxf(y1, by1);
    float xx2 = fminf(x2, bx2), yy2 = fminf(y2, by2);
    float iw = fmaxf(xx2 - xx1, 0.f), ih = fmaxf(yy2 - yy1, 0.f);
    float inter = iw * ih;
    float aj = (bx2 - bx1) * (by2 - by1);
    float iou = inter / (ai + aj - inter + 1e-9f);
    if (iou > 0.7f) m |= (1ull << jj);
  }
  masks[((size_t)b * 1000 + i) * 16 + w] = m;
}

#define NMS_CHUNK 448
__global__ __launch_bounds__(256) void nms_scan(const float* __restrict__ tb,
                                                const float* __restrict__ ts,
                                                const u64* __restrict__ masks,
                                                float* __restrict__ out) {
  int b = blockIdx.x;
  int tid = threadIdx.x;
  int lane = tid & 63;
  __shared__ u64 mchunk[NMS_CHUNK * 16];
  __shared__ float sts[1000];
  __shared__ int keep[POST_NMS_K];
  __shared__ int kcount;
  for (int i = tid; i < 1000; i += 256) sts[i] = ts[b * 1000 + i];
  if (tid == 0) kcount = 0;
  u64 rem = 0;
  int kreg = 0;
  const u64* M = masks + (size_t)b * 16000;
  for (int c0 = 0; c0 < 1000; c0 += NMS_CHUNK) {
    int cn = min(NMS_CHUNK, 1000 - c0);
    __syncthreads();
    if (kcount >= POST_NMS_K) break;
    for (int i = tid; i < cn * 16; i += 256) mchunk[i] = M[(size_t)c0 * 16 + i];
    __syncthreads();
    if (tid < 64) {
      for (int i = c0; i < c0 + cn; i++) {
        int kc_all = __shfl(kreg, 0);
        if (kc_all >= POST_NMS_K) break;
        u64 rw = __shfl(rem, i >> 6);
        bool sup = (rw >> (i & 63)) & 1ull;
        if (!sup) {
          if (lane < 16) rem |= mchunk[(i - c0) * 16 + lane];
          if (lane == 0 && sts[i] > -100000000.0f) { keep[kreg] = i; kreg++; }
        }
      }
      if (lane == 0) kcount = kreg;
    }
  }
  __syncthreads();
  int kc = kcount; if (kc > POST_NMS_K) kc = POST_NMS_K;
  for (int r = tid; r < POST_NMS_K; r += 256) {
    float v0 = 0.f, v1 = 0.f, v2 = 0.f, v3 = 0.f, v4 = 0.f;
    if (r < kc) {
      int i = keep[r];
      const float* bp = tb + (size_t)(b * 1000 + i) * 4;
      v0 = bp[0]; v1 = bp[1]; v2 = bp[2]; v3 = bp[3];
      v4 = sts[i];
    }
    float* op = out + (size_t)(b * POST_NMS_K + r) * 5;
    op[0] = v0; op[1] = v1; op[2] = v2; op[3] = v3; op[4] = v4;
  }
}

// ---------------------------------------------------------------- launch
extern "C" void kernel_launch(void* const* d_in, const int* in_sizes, int n_in,
                              void* d_out, int out_size, void* d_ws, size_t ws_size,
                              hipStream_t stream) {
  const float* feats[NLEV];
  for (int i = 0; i < NLEV; i++) feats[i] = (const float*)d_in[i];
  const float* conv_w = (const float*)d_in[5];
  const float* conv_b = (const float*)d_in[6];
  const float* cls_w  = (const float*)d_in[7];
  const float* cls_b  = (const float*)d_in[8];
  const float* box_w  = (const float*)d_in[9];
  const float* box_b  = (const float*)d_in[10];

  char* ws = (char*)d_ws;
  size_t off = 0;
  auto al = [&](size_t bytes) { size_t r = off; off = (off + bytes + 255) & ~(size_t)255; return r; };

  size_t o_Wb    = al((size_t)2 * 589824 * 2);
  size_t o_obj   = al((size_t)NB * ATOT * 4);
  size_t o_delta = al((size_t)NB * ATOT * 16);
  size_t o_boxes = al((size_t)NB * ATOT * 16);
  size_t o_msc   = al((size_t)NB * ATOT * 4);
  // zero region: ghist[4][NB][256] + cnts[4] + info[NB*16]
  size_t nzero   = (size_t)(4 * NB * 256 + 4 + NB * 16);
  size_t o_zero  = al(nzero * 4);
  size_t o_selu  = al((size_t)NB * 1024 * 4);
  size_t o_seli  = al((size_t)NB * 1024 * 4);
  size_t o_eqi   = al((size_t)NB * 4096 * 4);
  size_t o_tb    = al((size_t)NB * 1000 * 16);
  size_t o_ts    = al((size_t)NB * 1000 * 4);
  size_t o_mask  = al((size_t)NB * 16000 * 8);
  size_t PPmax   = 258 * 258;
  size_t o_Fb    = al((size_t)2 * NB * PPmax * 256 * 2);   // ~136 MB (reused per level)
  size_t o_X     = al((size_t)NB * 65536 * 256 * 4);       // ~134 MB (reused per level)
  if (off > ws_size) return;  // fail loudly (output stays poisoned)

  _Float16* Wb = (_Float16*)(ws + o_Wb);
  float* obj   = (float*)(ws + o_obj);
  float* delta = (float*)(ws + o_delta);
  float* boxes = (float*)(ws + o_boxes);
  float* msc   = (float*)(ws + o_msc);
  u32* ghist   = (u32*)(ws + o_zero);           // 4 passes x NB x 256
  u32* cnts    = ghist + 4 * NB * 256;
  u32* info    = cnts + 4;
  u32* sel_u   = (u32*)(ws + o_selu);
  u32* sel_i   = (u32*)(ws + o_seli);
  u32* eq_i    = (u32*)(ws + o_eqi);
  float* tb    = (float*)(ws + o_tb);
  float* ts    = (float*)(ws + o_ts);
  u64* masks   = (u64*)(ws + o_mask);
  _Float16* Fb = (_Float16*)(ws + o_Fb);
  float* X     = (float*)(ws + o_X);
  float* out   = (float*)d_out;

  hipMemsetAsync(ws + o_zero, 0, nzero * 4, stream);

  wt_split<<<2304, 256, 0, stream>>>(conv_w, Wb);

  const int hw[NLEV] = {256, 128, 64, 32, 16};
  const int aoff[NLEV] = {0, 196608, 245760, 258048, 261120};
  for (int l = 0; l < NLEV; l++) {
    int W = hw[l], HW = W * W, PP = (W + 2) * (W + 2);
    int H = 2 * (W + 2) + 2 * W;
    int hz = 2 * NB * H * 128;
    halo_zero<<<(hz + 255) / 256, 256, 0, stream>>>((u32*)Fb, W, PP, H);
    feat_split<<<dim3(HW / 32, NB), 256, 0, stream>>>(feats[l], Fb, W, HW, PP);
    conv_mfma<<<dim3(HW / 128, 2, NB), 256, 0, stream>>>(Fb, Wb, conv_b, X, W, HW, PP);
    epilogue_1x1<<<dim3(HW / 32, NB), 256, 0, stream>>>(X, cls_w, cls_b, box_w, box_b,
                                                        obj, delta, HW, aoff[l]);
  }

  int ngrid = NB * ATOT / 256;  // 2046, blocks never straddle batches
  decode_kernel<<<ngrid, 256, 0, stream>>>(obj, delta, boxes, msc, ghist);
  scan8<<<NB, 256, 0, stream>>>(ghist, info, 0);
  for (int p = 1; p <= 3; p++) {
    hist_pass<<<ngrid, 256, 0, stream>>>(msc, info, ghist + p * NB * 256,
                                         32 - 8 * p, 24 - 8 * p);
    scan8<<<NB, 256, 0, stream>>>(ghist + p * NB * 256, info, p);
  }
  collect_kernel<<<ngrid, 256, 0, stream>>>(msc, info, sel_u, sel_i, eq_i, cnts);
  finalize_topk<<<NB, 1024, 0, stream>>>(boxes, msc, info, sel_u, sel_i, eq_i, cnts, tb, ts);
  nms_mask<<<dim3(63, NB), 256, 0, stream>>>(tb, masks);
  nms_scan<<<NB, 256, 0, stream>>>(tb, ts, masks, out);
}

// Round 4
// 1773.516 us; speedup vs baseline: 3.0795x; 1.1815x over previous
//
#include <hip/hip_runtime.h>
#include <math.h>

typedef unsigned int u32;
typedef unsigned long long u64;
typedef __attribute__((ext_vector_type(8))) _Float16 f16x8;
typedef __attribute__((ext_vector_type(4))) float f32x4;

#define NLEV 5
#define ATOT 261888
#define NB 2
#define PRE_NMS_K 1000
#define POST_NMS_K 300

#define GLOBAL_AS __attribute__((address_space(1)))
#define LDS_AS __attribute__((address_space(3)))

__device__ __forceinline__ u32 sortable(float f) {
  u32 s = __float_as_uint(f);
  return (s & 0x80000000u) ? ~s : (s | 0x80000000u);
}

// ---------------------------------------------------------------- weight split
// Wb: [2 splits][co=256][k=2304], k = r*256+ci, r = ky*3+kx.
// Split 1 is scaled by 2048 so the residual stays in f16 normal range.
__global__ __launch_bounds__(256) void wt_split(const float* __restrict__ w,
                                                _Float16* __restrict__ Wb) {
  int t = blockIdx.x * 256 + threadIdx.x;   // 256*2304 total
  int k = t % 2304;
  int co = t / 2304;
  int r = k >> 8, ci = k & 255;
  int ky = r / 3, kx = r - ky * 3;
  float v = w[(((co << 8) + ci) * 3 + ky) * 3 + kx];
  _Float16 s0 = (_Float16)v;
  _Float16 s1 = (_Float16)((v - (float)s0) * 2048.0f);
  Wb[t] = s0;
  Wb[589824 + t] = s1;
}

// ---------------------------------------------------------------- halo zero
__global__ __launch_bounds__(256) void halo_zero(u32* __restrict__ Fb, int W, int PP, int H) {
  int t = blockIdx.x * 256 + threadIdx.x;
  int total = 2 * NB * H * 128;
  if (t >= total) return;
  int c = t & 127; int u = t >> 7;
  int hp = u % H; u /= H;
  int b = u % NB; int s = u / NB;
  int W2 = W + 2;
  int y, x;
  if (hp < 2 * W2) { y = (hp < W2) ? 0 : (W + 1); x = hp % W2; }
  else { int q = hp - 2 * W2; y = (q % W) + 1; x = (q < W) ? 0 : (W + 1); }
  size_t pidx = (size_t)y * W2 + x;
  Fb[(((size_t)s * NB + b) * PP + pidx) * 128 + c] = 0;
}

// ---------------------------------------------------------------- feature split
// NCHW fp32 -> NHWC-padded f16 x2 splits (split1 scaled x2048).
__global__ __launch_bounds__(256) void feat_split(const float* __restrict__ in,
                                                  _Float16* __restrict__ Fb,
                                                  int W, int HW, int PP) {
  int b = blockIdx.y;
  int pix0 = blockIdx.x * 32;
  int tid = threadIdx.x;
  __shared__ float sT[32 * 257];
  const float* inb = in + (size_t)b * 256 * HW;
#pragma unroll 4
  for (int i = 0; i < 32; i++) {
    int idx = i * 256 + tid;
    int ci = idx >> 5;
    int px = idx & 31;
    sT[px * 257 + ci] = inb[(size_t)ci * HW + pix0 + px];
  }
  __syncthreads();
  size_t SplitSz = (size_t)NB * PP * 256;
  int W2 = W + 2;
#pragma unroll 4
  for (int i = 0; i < 32; i++) {
    float v = sT[i * 257 + tid];
    _Float16 s0 = (_Float16)v;
    _Float16 s1 = (_Float16)((v - (float)s0) * 2048.0f);
    int pix = pix0 + i;
    int y = pix / W; int x = pix - y * W;
    size_t o = ((size_t)b * PP + (size_t)(y + 1) * W2 + (x + 1)) * 256 + tid;
    Fb[o] = s0; Fb[SplitSz + o] = s1;
  }
}

// ---------------------------------------------------------------- MFMA conv
// f16 2-split, 3 products: acc1 = A0*W0 ; acc2 = A0*W1' + A1'*W0 (both x2048)
// result = acc1 + acc2/2048.  ci-outer / tap-inner (L2 tap reuse).
// Double-buffered LDS: prefetch kt+1 while computing kt; one barrier per kt.
// NOTE: 128 acc regs (unified VGPR/AGPR) => 1 wave/SIMD; latency hidden by
// in-wave prefetch overlap, MFMA pipe fed by 16 independent tiles.
__global__ __launch_bounds__(256) void conv_mfma(
    const _Float16* __restrict__ Fb,   // [2][NB][PP][256]
    const _Float16* __restrict__ Wb,   // [2][256][2304]
    const float* __restrict__ cb,
    float* __restrict__ X,             // [NB][HW][256] fp32 (relu'd)
    int W, int HW, int PP) {
  int b = blockIdx.z;
  int n0 = blockIdx.y * 128;
  int m0 = blockIdx.x * 128;
  int tid = threadIdx.x;
  int lane = tid & 63;
  int wv = tid >> 6;
  int wm = wv & 1, wn = wv >> 1;
  int W2 = W + 2;

  __shared__ __align__(16) _Float16 sA[2][2][4096];   // [buf][split][pix*32ci]
  __shared__ __align__(16) _Float16 sB[2][2][4096];   // [buf][split][co*32ci]

  size_t SplitSz = (size_t)NB * PP * 256;
  int q = tid >> 2;              // 0..63
  int cisub = (tid & 3) * 8;

  long long aBase[2], bBase[2];
#pragma unroll
  for (int i = 0; i < 2; i++) {
    int p = m0 + q + 64 * i;
    int y = p / W; int x = p - y * W;
    aBase[i] = ((long long)b * PP + (long long)(y + 1) * W2 + (x + 1)) * 256 + cisub;
    int co = n0 + q + 64 * i;
    bBase[i] = (long long)co * 2304 + cisub;
  }

  int aoff[4], boff[4];
#pragma unroll
  for (int t4 = 0; t4 < 4; t4++) {
    aoff[t4] = (wm * 64 + t4 * 16 + (lane & 15)) * 32 + (lane >> 4) * 8;
    boff[t4] = (wn * 64 + t4 * 16 + (lane & 15)) * 32 + (lane >> 4) * 8;
  }

  f32x4 acc1[4][4], acc2[4][4];
#pragma unroll
  for (int mt = 0; mt < 4; mt++)
#pragma unroll
    for (int nt = 0; nt < 4; nt++) {
      acc1[mt][nt] = (f32x4){0.f, 0.f, 0.f, 0.f};
      acc2[mt][nt] = (f32x4){0.f, 0.f, 0.f, 0.f};
    }

  auto stage = [&](int kt, int buf) {
    int c = kt / 9;                 // ci-chunk (outer)
    int r = kt - c * 9;             // tap (inner -> L2 reuse)
    int rdy = r / 3;
    long long dOff = (long long)(rdy - 1) * W2 + (r - rdy * 3 - 1);
    long long aIt = dOff * 256 + c * 32;
    long long bIt = (long long)r * 256 + c * 32;
#pragma unroll
    for (int s = 0; s < 2; s++) {
      const _Float16* As = Fb + (size_t)s * SplitSz;
      const _Float16* Bs = Wb + (size_t)s * 589824;
#pragma unroll
      for (int i = 0; i < 2; i++) {
        __builtin_amdgcn_global_load_lds(
            (const GLOBAL_AS u32*)(As + aBase[i] + aIt),
            (LDS_AS u32*)((char*)&sA[buf][s][0] + 4096 * i + 1024 * wv), 16, 0, 0);
        __builtin_amdgcn_global_load_lds(
            (const GLOBAL_AS u32*)(Bs + bBase[i] + bIt),
            (LDS_AS u32*)((char*)&sB[buf][s][0] + 4096 * i + 1024 * wv), 16, 0, 0);
      }
    }
  };

  stage(0, 0);
  __syncthreads();                 // drain: buf0 ready

  for (int kt = 0; kt < 72; kt++) {
    int buf = kt & 1;
    if (kt < 71) stage(kt + 1, buf ^ 1);   // prefetch overlaps compute below
    __builtin_amdgcn_sched_barrier(0);     // pin prefetch issue above compute
    f16x8 af0[4], af1[4];
#pragma unroll
    for (int mt = 0; mt < 4; mt++) {
      af0[mt] = *(const f16x8*)&sA[buf][0][aoff[mt]];
      af1[mt] = *(const f16x8*)&sA[buf][1][aoff[mt]];
    }
#pragma unroll
    for (int nt = 0; nt < 4; nt++) {
      f16x8 b0 = *(const f16x8*)&sB[buf][0][boff[nt]];
      f16x8 b1 = *(const f16x8*)&sB[buf][1][boff[nt]];
#pragma unroll
      for (int mt = 0; mt < 4; mt++) {
        acc1[mt][nt] = __builtin_amdgcn_mfma_f32_16x16x32_f16(af0[mt], b0, acc1[mt][nt], 0, 0, 0);
        acc2[mt][nt] = __builtin_amdgcn_mfma_f32_16x16x32_f16(af0[mt], b1, acc2[mt][nt], 0, 0, 0);
        acc2[mt][nt] = __builtin_amdgcn_mfma_f32_16x16x32_f16(af1[mt], b0, acc2[mt][nt], 0, 0, 0);
      }
    }
    __syncthreads();   // drains prefetch (vmcnt) + my ds_reads (lgkm): both
                       // buffers safe for next iteration's stage/compute
  }

  // combine + bias + relu + store (C/D layout: col=lane&15, row=(lane>>4)*4+reg)
  const float inv2048 = 1.0f / 2048.0f;
  float* Xb = X + (size_t)b * HW * 256;
#pragma unroll
  for (int nt = 0; nt < 4; nt++) {
    int ch = n0 + wn * 64 + nt * 16 + (lane & 15);
    float bias = cb[ch];
#pragma unroll
    for (int mt = 0; mt < 4; mt++) {
      int mb = m0 + wm * 64 + mt * 16 + (lane >> 4) * 4;
      f32x4 c1 = acc1[mt][nt];
      f32x4 c2 = acc2[mt][nt];
#pragma unroll
      for (int rr = 0; rr < 4; rr++) {
        float v = c1[rr] + c2[rr] * inv2048 + bias;
        Xb[(size_t)(mb + rr) * 256 + ch] = v > 0.f ? v : 0.f;
      }
    }
  }
}

// ---------------------------------------------------------------- 1x1 epilogue
__global__ __launch_bounds__(256) void epilogue_1x1(
    const float* __restrict__ X, const float* __restrict__ clsw,
    const float* __restrict__ clsb, const float* __restrict__ boxw,
    const float* __restrict__ boxb, float* __restrict__ obj,
    float* __restrict__ delta, int HW, int lvloff) {
  int b = blockIdx.y;
  int pix0 = blockIdx.x * 32;
  int tid = threadIdx.x;
  __shared__ float sX[32 * 257];
  __shared__ float sW[15 * 257];
  const float4* X4 = (const float4*)(X + ((size_t)b * HW + pix0) * 256);
  for (int i = tid; i < 32 * 64; i += 256) {
    int p = i >> 6, c4 = i & 63;
    float4 v = X4[p * 64 + c4];
    float* dst = &sX[p * 257 + c4 * 4];
    dst[0] = v.x; dst[1] = v.y; dst[2] = v.z; dst[3] = v.w;
  }
  for (int t = tid; t < 15 * 256; t += 256) {
    int ch = t >> 8, ci = t & 255;
    sW[ch * 257 + ci] = (ch < 3) ? clsw[(ch << 8) + ci] : boxw[((ch - 3) << 8) + ci];
  }
  __syncthreads();
  for (int o = tid; o < 32 * 15; o += 256) {
    int m = o / 15;
    int ch = o - m * 15;
    const float* xr = &sX[m * 257];
    const float* wr = &sW[ch * 257];
    float s0 = 0.f, s1 = 0.f, s2 = 0.f, s3 = 0.f;
#pragma unroll 4
    for (int ci = 0; ci < 256; ci += 4) {
      s0 += xr[ci] * wr[ci];
      s1 += xr[ci + 1] * wr[ci + 1];
      s2 += xr[ci + 2] * wr[ci + 2];
      s3 += xr[ci + 3] * wr[ci + 3];
    }
    float s = (s0 + s1) + (s2 + s3);
    int gm = pix0 + m;
    size_t aoff = (size_t)b * ATOT + lvloff + (size_t)gm * 3;
    if (ch < 3) {
      obj[aoff + ch] = s + clsb[ch];
    } else {
      int bc = ch - 3;
      delta[(aoff + (bc >> 2)) * 4 + (bc & 3)] = s + boxb[bc];
    }
  }
}

// ---------------------------------------------------------------- decode (+ radix pass 0)
__global__ __launch_bounds__(256) void decode_kernel(
    const float* __restrict__ obj, const float* __restrict__ delta,
    float* __restrict__ boxes, float* __restrict__ mscore,
    u32* __restrict__ gh0) {
  __shared__ u32 lh[256];
  int tid = threadIdx.x;
  lh[tid] = 0;
  __syncthreads();
  int t = blockIdx.x * 256 + tid;
  int b = t / ATOT;
  int a = t - b * ATOT;
  int off, hwsh, stsh;
  float size;
  if (a < 196608)       { off = 0;      hwsh = 8; stsh = 2; size = 32.f; }
  else if (a < 245760)  { off = 196608; hwsh = 7; stsh = 3; size = 64.f; }
  else if (a < 258048)  { off = 245760; hwsh = 6; stsh = 4; size = 128.f; }
  else if (a < 261120)  { off = 258048; hwsh = 5; stsh = 5; size = 256.f; }
  else                  { off = 261120; hwsh = 4; stsh = 6; size = 512.f; }
  int rel = a - off;
  int pix = rel / 3;
  int ar = rel - pix * 3;
  int y = pix >> hwsh;
  int x = pix & ((1 << hwsh) - 1);
  float ratio = (ar == 0) ? 0.5f : ((ar == 1) ? 1.0f : 2.0f);
  float sq = sqrtf(ratio);
  float hh = size * sq;
  float wwv = size / sq;
  float sx = (float)(x << stsh);
  float sy = (float)(y << stsh);
  float wh = wwv * 0.5f, hhh = hh * 0.5f;
  float a0 = sx - wh, a1 = sy - hhh, a2 = sx + wh, a3 = sy + hhh;
  float aw = a2 - a0, ah = a3 - a1;
  float ax = a0 + aw * 0.5f, ay = a1 + ah * 0.5f;
  const float* dp = delta + (size_t)t * 4;
  float dx = dp[0], dy = dp[1], dw = dp[2], dh = dp[3];
  float cx = dx * aw + ax;
  float cy = dy * ah + ay;
  float pw = expf(dw) * aw;
  float ph = expf(dh) * ah;
  float x1 = cx - pw * 0.5f, y1 = cy - ph * 0.5f;
  float x2 = cx + pw * 0.5f, y2 = cy + ph * 0.5f;
  x1 = fminf(fmaxf(x1, 0.f), 1024.f);
  y1 = fminf(fmaxf(y1, 0.f), 1024.f);
  x2 = fminf(fmaxf(x2, 0.f), 1024.f);
  y2 = fminf(fmaxf(y2, 0.f), 1024.f);
  float wsv = x2 - x1, hsv = y2 - y1;
  bool valid = (wsv >= 1.f) && (hsv >= 1.f);
  float o = obj[t];
  float sc = 1.f / (1.f + expf(-o));
  float ms = valid ? sc : -1e9f;
  float* bp = boxes + (size_t)t * 4;
  bp[0] = x1; bp[1] = y1; bp[2] = x2; bp[3] = y2;
  mscore[t] = ms;
  atomicAdd(&lh[sortable(ms) >> 24], 1u);
  __syncthreads();
  u32 v = lh[tid];
  if (v) atomicAdd(&gh0[b * 256 + tid], v);
}

// ---------------------------------------------------------------- radix passes 1..3
__global__ __launch_bounds__(256) void hist_pass(const float* __restrict__ mscore,
                                                 const u32* __restrict__ info,
                                                 u32* __restrict__ gh,
                                                 int pshift, int bshift) {
  __shared__ u32 lh[256];
  int tid = threadIdx.x;
  lh[tid] = 0;
  __syncthreads();
  int t = blockIdx.x * 256 + tid;
  int b = t / ATOT;
  u32 u = sortable(mscore[t]);
  if ((u >> pshift) == info[b * 16]) atomicAdd(&lh[(u >> bshift) & 255u], 1u);
  __syncthreads();
  u32 v = lh[tid];
  if (v) atomicAdd(&gh[b * 256 + tid], v);
}

__global__ __launch_bounds__(256) void scan8(const u32* __restrict__ gh,
                                             u32* __restrict__ info, int mode) {
  int b = blockIdx.x;
  int tid = threadIdx.x;
  __shared__ u32 h[256];
  h[tid] = gh[b * 256 + tid];
  __syncthreads();
  if (tid == 0) {
    u32* inf = &info[b * 16];
    u32 K = (u32)PRE_NMS_K - inf[1];
    u32 c = 0;
    int bstar = 0;
    for (int j = 255; j >= 0; j--) {
      u32 hv = h[j];
      if (c + hv >= K) { bstar = j; break; }
      c += hv;
    }
    inf[0] = (inf[0] << 8) | (u32)bstar;
    inf[1] += c;
    if (mode == 3) inf[4] = K - c;
  }
}

__global__ __launch_bounds__(256) void collect_kernel(
    const float* __restrict__ mscore, const u32* __restrict__ info,
    u32* __restrict__ sel_u, u32* __restrict__ sel_i, u32* __restrict__ eq_i,
    u32* __restrict__ cnts) {
  int t = blockIdx.x * 256 + threadIdx.x;
  int b = t / ATOT;
  int a = t - b * ATOT;
  u32 ustar = info[b * 16];
  u32 u = sortable(mscore[t]);
  if (u > ustar) {
    u32 p = atomicAdd(&cnts[b], 1u);
    if (p < 1024u) { sel_u[b * 1024 + p] = u; sel_i[b * 1024 + p] = (u32)a; }
  } else if (u == ustar) {
    u32 p = atomicAdd(&cnts[2 + b], 1u);
    if (p < 4096u) eq_i[b * 4096 + p] = (u32)a;
  }
}

__global__ __launch_bounds__(1024) void finalize_topk(
    const float* __restrict__ boxes, const float* __restrict__ mscore,
    const u32* __restrict__ info, const u32* __restrict__ sel_u,
    const u32* __restrict__ sel_i, const u32* __restrict__ eq_i,
    const u32* __restrict__ cnts, float* __restrict__ tb, float* __restrict__ ts) {
  int b = blockIdx.x, tid = threadIdx.x;
  const u32* inf = info + b * 16;
  u32 nsel = cnts[b];       if (nsel > 1000u) nsel = 1000u;
  u32 neq = cnts[2 + b];    if (neq > 4096u) neq = 4096u;
  u32 take = inf[4];        if (take > 1000u) take = 1000u;
  u32 ustar = inf[0];
  u32 tot = nsel + take;    if (tot > 1024u) tot = 1024u;

  __shared__ u32 eqbuf[4096];
  __shared__ u64 keys[1024];
  for (int i = tid; i < 4096; i += 1024) eqbuf[i] = (i < (int)neq) ? eq_i[b * 4096 + i] : 0xFFFFFFFFu;
  __syncthreads();
  for (int k = 2; k <= 4096; k <<= 1)
    for (int j = k >> 1; j > 0; j >>= 1) {
      for (int i = tid; i < 4096; i += 1024) {
        int p = i ^ j;
        if (p > i) {
          u32 x = eqbuf[i], y = eqbuf[p];
          bool up = ((i & k) == 0);
          if (up ? (x > y) : (x < y)) { eqbuf[i] = y; eqbuf[p] = x; }
        }
      }
      __syncthreads();
    }
  u64 kv = 0;
  if (tid < (int)nsel) kv = ((u64)sel_u[b * 1024 + tid] << 32) | (u64)(0xFFFFFFFFu - sel_i[b * 1024 + tid]);
  else if (tid < (int)tot) kv = ((u64)ustar << 32) | (u64)(0xFFFFFFFFu - eqbuf[tid - nsel]);
  keys[tid] = kv;
  __syncthreads();
  for (int k = 2; k <= 1024; k <<= 1)
    for (int j = k >> 1; j > 0; j >>= 1) {
      int p = tid ^ j;
      if (p > tid) {
        u64 x = keys[tid], y = keys[p];
        bool up = ((tid & k) == 0);
        if (up ? (x < y) : (x > y)) { keys[tid] = y; keys[p] = x; }
      }
      __syncthreads();
    }
  if (tid < PRE_NMS_K) {
    u32 idx = 0xFFFFFFFFu - (u32)(keys[tid] & 0xFFFFFFFFull);
    size_t g = (size_t)b * ATOT + idx;
    float4 bx = *(const float4*)(boxes + g * 4);
    *(float4*)(tb + (size_t)(b * PRE_NMS_K + tid) * 4) = bx;
    ts[b * PRE_NMS_K + tid] = mscore[g];
  }
}

// ---------------------------------------------------------------- NMS
__global__ __launch_bounds__(256) void nms_mask(const float* __restrict__ tb,
                                                u64* __restrict__ masks) {
  int t = blockIdx.x * 256 + threadIdx.x;
  int b = blockIdx.y;
  if (t >= 16000) return;
  int i = t >> 4, w = t & 15;
  const float* B = tb + (size_t)b * 4000;
  float x1 = B[i * 4], y1 = B[i * 4 + 1], x2 = B[i * 4 + 2], y2 = B[i * 4 + 3];
  float ai = (x2 - x1) * (y2 - y1);
  u64 m = 0;
  int j0 = w << 6;
#pragma unroll 4
  for (int jj = 0; jj < 64; jj++) {
    int j = j0 + jj;
    if (j <= i || j >= 1000) continue;
    float bx1 = B[j * 4], by1 = B[j * 4 + 1], bx2 = B[j * 4 + 2], by2 = B[j * 4 + 3];
    float xx1 = fmaxf(x1, bx1), yy1 = fmaxf(y1, by1);
    float xx2 = fminf(x2, bx2), yy2 = fminf(y2, by2);
    float iw = fmaxf(xx2 - xx1, 0.f), ih = fmaxf(yy2 - yy1, 0.f);
    float inter = iw * ih;
    float aj = (bx2 - bx1) * (by2 - by1);
    float iou = inter / (ai + aj - inter + 1e-9f);
    if (iou > 0.7f) m |= (1ull << jj);
  }
  masks[((size_t)b * 1000 + i) * 16 + w] = m;
}

#define NMS_CHUNK 448
__global__ __launch_bounds__(256) void nms_scan(const float* __restrict__ tb,
                                                const float* __restrict__ ts,
                                                const u64* __restrict__ masks,
                                                float* __restrict__ out) {
  int b = blockIdx.x;
  int tid = threadIdx.x;
  int lane = tid & 63;
  __shared__ u64 mchunk[NMS_CHUNK * 16];
  __shared__ float sts[1000];
  __shared__ int keep[POST_NMS_K];
  __shared__ int kcount;
  for (int i = tid; i < 1000; i += 256) sts[i] = ts[b * 1000 + i];
  if (tid == 0) kcount = 0;
  u64 rem = 0;
  int kreg = 0;
  const u64* M = masks + (size_t)b * 16000;
  for (int c0 = 0; c0 < 1000; c0 += NMS_CHUNK) {
    int cn = min(NMS_CHUNK, 1000 - c0);
    __syncthreads();
    if (kcount >= POST_NMS_K) break;
    for (int i = tid; i < cn * 16; i += 256) mchunk[i] = M[(size_t)c0 * 16 + i];
    __syncthreads();
    if (tid < 64) {
      for (int i = c0; i < c0 + cn; i++) {
        int kc_all = __shfl(kreg, 0);
        if (kc_all >= POST_NMS_K) break;
        u64 rw = __shfl(rem, i >> 6);
        bool sup = (rw >> (i & 63)) & 1ull;
        if (!sup) {
          if (lane < 16) rem |= mchunk[(i - c0) * 16 + lane];
          if (lane == 0 && sts[i] > -100000000.0f) { keep[kreg] = i; kreg++; }
        }
      }
      if (lane == 0) kcount = kreg;
    }
  }
  __syncthreads();
  int kc = kcount; if (kc > POST_NMS_K) kc = POST_NMS_K;
  for (int r = tid; r < POST_NMS_K; r += 256) {
    float v0 = 0.f, v1 = 0.f, v2 = 0.f, v3 = 0.f, v4 = 0.f;
    if (r < kc) {
      int i = keep[r];
      const float* bp = tb + (size_t)(b * 1000 + i) * 4;
      v0 = bp[0]; v1 = bp[1]; v2 = bp[2]; v3 = bp[3];
      v4 = sts[i];
    }
    float* op = out + (size_t)(b * POST_NMS_K + r) * 5;
    op[0] = v0; op[1] = v1; op[2] = v2; op[3] = v3; op[4] = v4;
  }
}

// ---------------------------------------------------------------- launch
extern "C" void kernel_launch(void* const* d_in, const int* in_sizes, int n_in,
                              void* d_out, int out_size, void* d_ws, size_t ws_size,
                              hipStream_t stream) {
  const float* feats[NLEV];
  for (int i = 0; i < NLEV; i++) feats[i] = (const float*)d_in[i];
  const float* conv_w = (const float*)d_in[5];
  const float* conv_b = (const float*)d_in[6];
  const float* cls_w  = (const float*)d_in[7];
  const float* cls_b  = (const float*)d_in[8];
  const float* box_w  = (const float*)d_in[9];
  const float* box_b  = (const float*)d_in[10];

  char* ws = (char*)d_ws;
  size_t off = 0;
  auto al = [&](size_t bytes) { size_t r = off; off = (off + bytes + 255) & ~(size_t)255; return r; };

  size_t o_Wb    = al((size_t)2 * 589824 * 2);
  size_t o_obj   = al((size_t)NB * ATOT * 4);
  size_t o_delta = al((size_t)NB * ATOT * 16);
  size_t o_boxes = al((size_t)NB * ATOT * 16);
  size_t o_msc   = al((size_t)NB * ATOT * 4);
  // zero region: ghist[4][NB][256] + cnts[4] + info[NB*16]
  size_t nzero   = (size_t)(4 * NB * 256 + 4 + NB * 16);
  size_t o_zero  = al(nzero * 4);
  size_t o_selu  = al((size_t)NB * 1024 * 4);
  size_t o_seli  = al((size_t)NB * 1024 * 4);
  size_t o_eqi   = al((size_t)NB * 4096 * 4);
  size_t o_tb    = al((size_t)NB * 1000 * 16);
  size_t o_ts    = al((size_t)NB * 1000 * 4);
  size_t o_mask  = al((size_t)NB * 16000 * 8);
  size_t PPmax   = 258 * 258;
  size_t o_Fb    = al((size_t)2 * NB * PPmax * 256 * 2);   // ~136 MB (reused per level)
  size_t o_X     = al((size_t)NB * 65536 * 256 * 4);       // ~134 MB (reused per level)
  if (off > ws_size) return;  // fail loudly (output stays poisoned)

  _Float16* Wb = (_Float16*)(ws + o_Wb);
  float* obj   = (float*)(ws + o_obj);
  float* delta = (float*)(ws + o_delta);
  float* boxes = (float*)(ws + o_boxes);
  float* msc   = (float*)(ws + o_msc);
  u32* ghist   = (u32*)(ws + o_zero);           // 4 passes x NB x 256
  u32* cnts    = ghist + 4 * NB * 256;
  u32* info    = cnts + 4;
  u32* sel_u   = (u32*)(ws + o_selu);
  u32* sel_i   = (u32*)(ws + o_seli);
  u32* eq_i    = (u32*)(ws + o_eqi);
  float* tb    = (float*)(ws + o_tb);
  float* ts    = (float*)(ws + o_ts);
  u64* masks   = (u64*)(ws + o_mask);
  _Float16* Fb = (_Float16*)(ws + o_Fb);
  float* X     = (float*)(ws + o_X);
  float* out   = (float*)d_out;

  hipMemsetAsync(ws + o_zero, 0, nzero * 4, stream);

  wt_split<<<2304, 256, 0, stream>>>(conv_w, Wb);

  const int hw[NLEV] = {256, 128, 64, 32, 16};
  const int aoff[NLEV] = {0, 196608, 245760, 258048, 261120};
  for (int l = 0; l < NLEV; l++) {
    int W = hw[l], HW = W * W, PP = (W + 2) * (W + 2);
    int H = 2 * (W + 2) + 2 * W;
    int hz = 2 * NB * H * 128;
    halo_zero<<<(hz + 255) / 256, 256, 0, stream>>>((u32*)Fb, W, PP, H);
    feat_split<<<dim3(HW / 32, NB), 256, 0, stream>>>(feats[l], Fb, W, HW, PP);
    conv_mfma<<<dim3(HW / 128, 2, NB), 256, 0, stream>>>(Fb, Wb, conv_b, X, W, HW, PP);
    epilogue_1x1<<<dim3(HW / 32, NB), 256, 0, stream>>>(X, cls_w, cls_b, box_w, box_b,
                                                        obj, delta, HW, aoff[l]);
  }

  int ngrid = NB * ATOT / 256;  // 2046, blocks never straddle batches
  decode_kernel<<<ngrid, 256, 0, stream>>>(obj, delta, boxes, msc, ghist);
  scan8<<<NB, 256, 0, stream>>>(ghist, info, 0);
  for (int p = 1; p <= 3; p++) {
    hist_pass<<<ngrid, 256, 0, stream>>>(msc, info, ghist + p * NB * 256,
                                         32 - 8 * p, 24 - 8 * p);
    scan8<<<NB, 256, 0, stream>>>(ghist + p * NB * 256, info, p);
  }
  collect_kernel<<<ngrid, 256, 0, stream>>>(msc, info, sel_u, sel_i, eq_i, cnts);
  finalize_topk<<<NB, 1024, 0, stream>>>(boxes, msc, info, sel_u, sel_i, eq_i, cnts, tb, ts);
  nms_mask<<<dim3(63, NB), 256, 0, stream>>>(tb, masks);
  nms_scan<<<NB, 256, 0, stream>>>(tb, ts, masks, out);
}